// Round 10
// baseline (176.005 us; speedup 1.0000x reference)
//
#include <hip/hip_runtime.h>
#include <hip/hip_bf16.h>

typedef __bf16 bf16_t;
typedef __bf16 bf16x8 __attribute__((ext_vector_type(8)));
typedef __bf16 bf16x4 __attribute__((ext_vector_type(4)));
typedef float f32x4 __attribute__((ext_vector_type(4)));

constexpr int LD = 3072;

#define MFMA_16x16x32(a, b, c) __builtin_amdgcn_mfma_f32_16x16x32_bf16((a), (b), (c), 0, 0, 0)

#define GLOAD_LDS16(g, l)                                               \
  __builtin_amdgcn_global_load_lds(                                     \
      (const __attribute__((address_space(1))) void*)(g),               \
      (__attribute__((address_space(3))) void*)(l), 16, 0, 0)

#define TRREAD(dst, addr, imm) \
  asm volatile("ds_read_b64_tr_b16 %0, %1 offset:" imm : "=v"(dst) : "v"(addr))

#define BAR __builtin_amdgcn_s_barrier()
#define LGKM0 do { asm volatile("s_waitcnt lgkmcnt(0)" ::: "memory"); \
                   __builtin_amdgcn_sched_barrier(0); } while (0)

// ---------------- fp32 -> bf16 convert (16B-store vectorized) ----------------
__global__ void cvt_kernel(const float* __restrict__ in, bf16_t* __restrict__ out, int n8) {
  int i = blockIdx.x * blockDim.x + threadIdx.x;
  if (i >= n8) return;
  const float4 a = reinterpret_cast<const float4*>(in)[2 * i];
  const float4 c = reinterpret_cast<const float4*>(in)[2 * i + 1];
  bf16x8 o;
  o[0] = (bf16_t)a.x; o[1] = (bf16_t)a.y; o[2] = (bf16_t)a.z; o[3] = (bf16_t)a.w;
  o[4] = (bf16_t)c.x; o[5] = (bf16_t)c.y; o[6] = (bf16_t)c.z; o[7] = (bf16_t)c.w;
  reinterpret_cast<bf16x8*>(out)[i] = o;
}

// ------------- transpose + convert: out[c][r] = (bf16) in[r][c] -------------
__global__ void tcvt_kernel(const float* __restrict__ in, bf16_t* __restrict__ out, int R, int C) {
  __shared__ float tile[32][33];
  const int c0 = blockIdx.x * 32, r0 = blockIdx.y * 32;
  const int tx = threadIdx.x & 31, ty = threadIdx.x >> 5;  // 32 x 8
#pragma unroll
  for (int i = 0; i < 32; i += 8)
    tile[ty + i][tx] = in[(size_t)(r0 + ty + i) * C + (c0 + tx)];
  __syncthreads();
#pragma unroll
  for (int i = 0; i < 32; i += 8)
    out[(size_t)(c0 + ty + i) * R + (r0 + tx)] = (bf16_t)tile[tx][ty + i];
}

// ------------- GEMM1 (QKV): 256x256 tile, 8-phase, counted vmcnt -------------
__global__ __launch_bounds__(512, 2) void gemm_qkv_256(
    const bf16_t* __restrict__ A, const bf16_t* __restrict__ Bt,
    bf16_t* __restrict__ C, float q_scale) {
  constexpr int K = 1024;
  extern __shared__ char smem[];
  char* asB = smem;           // 64 KB: A [2][2][128][64]
  char* bsB = smem + 65536;   // 64 KB: B

  const int t = threadIdx.x;
  const int lane = t & 63, wave = t >> 6;
  const int l15 = lane & 15, lg = lane >> 4;
  const int wr = wave >> 2, wc = wave & 3;

  const int bid = blockIdx.x;
  const int wg = (bid & 7) * 48 + (bid >> 3);
  const int brow = (wg & 31) * 256;
  const int bcol = (wg >> 5) * 256;

  const int srow = t >> 3;
  const int schk = (t & 7) ^ (srow & 7);
  const bf16_t* aS = A + (size_t)(brow + srow) * K + schk * 8;
  const bf16_t* bS = Bt + (size_t)(bcol + srow) * K + schk * 8;
  const int ldst = t * 8;

#define STG_A(T, H) do {                                                      \
    const bf16_t* _s = aS + (size_t)((H) * 128) * K + (T) * 64;               \
    bf16_t* _d = (bf16_t*)(asB + ((T) & 1) * 32768 + (H) * 16384) + ldst;     \
    GLOAD_LDS16(_s, _d);                                                      \
    GLOAD_LDS16(_s + (size_t)64 * K, _d + 4096);                              \
  } while (0)
#define STG_B(T, H) do {                                                      \
    const bf16_t* _s = bS + (size_t)((H) * 128) * K + (T) * 64;               \
    bf16_t* _d = (bf16_t*)(bsB + ((T) & 1) * 32768 + (H) * 16384) + ldst;     \
    GLOAD_LDS16(_s, _d);                                                      \
    GLOAD_LDS16(_s + (size_t)64 * K, _d + 4096);                              \
  } while (0)

  const int rx = l15 & 7;
  const unsigned c0 = ((unsigned)(lg ^ rx)) << 4;
  const unsigned c1 = ((unsigned)((4 | lg) ^ rx)) << 4;
  const unsigned a_rd = (unsigned)(wr * 16384 + l15 * 128);
  const unsigned b_rd = (unsigned)((wc >> 1) * 16384 + (wc & 1) * 8192 + l15 * 128);

  f32x4 acc[8][4] = {};
  bf16x8 af[4][2], bfr[2][2];

#define RD_AF(BUF, MH) do { _Pragma("unroll")                                 \
    for (int m = 0; m < 4; ++m) {                                             \
      const char* _p = asB + (BUF) * 32768 + a_rd + ((MH) * 4 + m) * 2048;    \
      af[m][0] = *(const bf16x8*)(_p + c0);                                   \
      af[m][1] = *(const bf16x8*)(_p + c1); } } while (0)
#define RD_BF(BUF, NH) do { _Pragma("unroll")                                 \
    for (int n = 0; n < 2; ++n) {                                             \
      const char* _p = bsB + (BUF) * 32768 + b_rd + ((NH) * 2 + n) * 2048;    \
      bfr[n][0] = *(const bf16x8*)(_p + c0);                                  \
      bfr[n][1] = *(const bf16x8*)(_p + c1); } } while (0)
#define MM16(MH, NH) do {                                                     \
    __builtin_amdgcn_s_setprio(1);                                            \
    _Pragma("unroll")                                                         \
    for (int m = 0; m < 4; ++m) { _Pragma("unroll")                           \
      for (int n = 0; n < 2; ++n) {                                           \
        acc[(MH)*4+m][(NH)*2+n] =                                             \
            MFMA_16x16x32(af[m][0], bfr[n][0], acc[(MH)*4+m][(NH)*2+n]);      \
        acc[(MH)*4+m][(NH)*2+n] =                                             \
            MFMA_16x16x32(af[m][1], bfr[n][1], acc[(MH)*4+m][(NH)*2+n]); } }  \
    __builtin_amdgcn_s_setprio(0); } while (0)

  STG_A(0, 0); STG_A(0, 1); STG_B(0, 0); STG_B(0, 1); STG_A(1, 0);
  asm volatile("s_waitcnt vmcnt(2)" ::: "memory");
  BAR;

  for (int i = 0; i < 8; ++i) {
    const int T1 = 2 * i + 1, T2 = 2 * i + 2, T3 = 2 * i + 3;
    const bool pf = (i < 7);
    STG_A(T1, 1);
    RD_AF(0, 0); RD_BF(0, 0);
    BAR; LGKM0; MM16(0, 0); BAR;
    STG_B(T1, 0);
    RD_BF(0, 1);
    BAR; LGKM0; MM16(0, 1); BAR;
    STG_B(T1, 1);
    RD_AF(0, 1);
    BAR; LGKM0; MM16(1, 1); BAR;
    if (pf) STG_A(T2, 0);
    RD_BF(0, 0);
    BAR; LGKM0; MM16(1, 0);
    if (pf) asm volatile("s_waitcnt vmcnt(2)" ::: "memory");
    else    asm volatile("s_waitcnt vmcnt(0)" ::: "memory");
    BAR;
    if (pf) STG_A(T2, 1);
    RD_AF(1, 0); RD_BF(1, 0);
    BAR; LGKM0; MM16(0, 0); BAR;
    if (pf) STG_B(T2, 0);
    RD_BF(1, 1);
    BAR; LGKM0; MM16(0, 1); BAR;
    if (pf) STG_B(T2, 1);
    RD_AF(1, 1);
    BAR; LGKM0; MM16(1, 1); BAR;
    if (pf) STG_A(T3, 0);
    RD_BF(1, 0);
    BAR; LGKM0; MM16(1, 0);
    asm volatile("s_waitcnt vmcnt(2)" ::: "memory");
    BAR;
  }

  const float sc = (bcol < 1024) ? q_scale : 1.0f;
  const int crow0 = brow + wr * 128 + lg * 4;
  const int ccol0 = bcol + wc * 64 + l15;
#pragma unroll
  for (int m = 0; m < 8; ++m)
#pragma unroll
    for (int n = 0; n < 4; ++n)
#pragma unroll
      for (int r = 0; r < 4; ++r)
        C[(size_t)(crow0 + m * 16 + r) * 3072 + ccol0 + n * 16] =
            (bf16_t)(acc[m][n][r] * sc);
#undef STG_A
#undef STG_B
#undef RD_AF
#undef RD_BF
#undef MM16
}

// ------------- bf16 GEMM (128²): C[M][N] = A[M][K] * Bt[N][K]^T -------------
template <typename OutT>
__global__ __launch_bounds__(256) void gemm_bt_kernel(
    const bf16_t* __restrict__ A, const bf16_t* __restrict__ Bt, OutT* __restrict__ C,
    int M, int N, int K, int q_cols, float q_scale) {
  __shared__ bf16_t As[2][4096];
  __shared__ bf16_t Bs[2][4096];
  const int tid = threadIdx.x;
  const int lane = tid & 63;
  const int wave = tid >> 6;
  const int l15 = lane & 15, lg = lane >> 4;
  const int wr = wave >> 1, wc = wave & 1;
  const int brow = blockIdx.y * 128, bcol = blockIdx.x * 128;

  f32x4 acc[4][4] = {};

  const int srow = tid >> 2;
  const int scol = (tid & 3) * 8;
  const bf16_t* Ag = A + (size_t)(brow + srow) * K + scol;
  const bf16_t* Bg = Bt + (size_t)(bcol + srow) * K + scol;

  {
    bf16_t* aw = &As[0][wave * 512];
    bf16_t* bw = &Bs[0][wave * 512];
    GLOAD_LDS16(Ag, aw);
    GLOAD_LDS16(Ag + (size_t)64 * K, aw + 2048);
    GLOAD_LDS16(Bg, bw);
    GLOAD_LDS16(Bg + (size_t)64 * K, bw + 2048);
  }
  __syncthreads();

  const int nsteps = K >> 5;
  for (int i = 0; i < nsteps; i++) {
    if (i + 1 < nsteps) {
      const int k0 = (i + 1) << 5;
      bf16_t* aw = &As[(i + 1) & 1][wave * 512];
      bf16_t* bw = &Bs[(i + 1) & 1][wave * 512];
      GLOAD_LDS16(Ag + k0, aw);
      GLOAD_LDS16(Ag + k0 + (size_t)64 * K, aw + 2048);
      GLOAD_LDS16(Bg + k0, bw);
      GLOAD_LDS16(Bg + k0 + (size_t)64 * K, bw + 2048);
    }
    const bf16_t* as = As[i & 1];
    const bf16_t* bs = Bs[i & 1];
    bf16x8 af[4], bfr[4];
#pragma unroll
    for (int j = 0; j < 4; j++)
      af[j] = *reinterpret_cast<const bf16x8*>(as + (wr * 64 + j * 16 + l15) * 32 + lg * 8);
#pragma unroll
    for (int j = 0; j < 4; j++)
      bfr[j] = *reinterpret_cast<const bf16x8*>(bs + (wc * 64 + j * 16 + l15) * 32 + lg * 8);
#pragma unroll
    for (int j = 0; j < 4; j++)
#pragma unroll
      for (int k = 0; k < 4; k++)
        acc[j][k] = MFMA_16x16x32(af[j], bfr[k], acc[j][k]);
    __syncthreads();
  }

  const float sc = (bcol < q_cols) ? q_scale : 1.0f;
#pragma unroll
  for (int i = 0; i < 4; i++)
#pragma unroll
    for (int j = 0; j < 4; j++)
#pragma unroll
      for (int r = 0; r < 4; r++) {
        const size_t row = (size_t)(brow + wr * 64 + i * 16 + lg * 4 + r);
        const size_t col = (size_t)(bcol + wc * 64 + j * 16 + l15);
        C[row * N + col] = (OutT)(acc[i][j][r] * sc);
      }
}

// ------------- fused attention (v9: KVBLK=128 tile-pair, cross-tile overlap) --
// Per pair j: stage pair j+1 (8 gload) -> QK_A -> trA issue -> KB ds_reads ->
// lgkm(0) -> {QK_B MFMA || softmax_A VALU} -> trB issue -> {PV_A || softmax_B}
// -> lgkm(0) -> PV_B -> __syncthreads (implicit vmcnt(0) drains stage).
// All waits are FULL drains (immune to count errors). One barrier per pair.
__device__ __forceinline__ unsigned pack_bf16_pair(float a, float b) {
  union { __hip_bfloat162 h; unsigned u; } c;
  c.h = __float22bfloat162_rn(float2{a, b});  // v_cvt_pk_bf16_f32
  return c.u;
}

__global__ __launch_bounds__(256, 3) void attn_kernel(const bf16_t* __restrict__ qkv,
                                                      bf16_t* __restrict__ ctx) {
  __shared__ bf16_t Ks[2][8192];  // [pair][tile*4096], swizzled K (32 KB)
  __shared__ bf16_t Vs[2][8192];  // [pair][tile*4096], pi-subtiled V (32 KB)
  const int tid = threadIdx.x, lane = tid & 63, wave = tid >> 6;
  const int l15 = lane & 15, lg = (lane >> 4) & 3;
  const int flat = blockIdx.x;
  const int xcd = flat & 7, rr = flat >> 3;
  const int qt = rr & 7;
  const int hb = xcd * 16 + (rr >> 3);
  const int h = hb & 15, b = hb >> 4;
  const size_t base = (size_t)b * 1024 * LD;
  const int qbase = qt * 128 + wave * 32;

  bf16x8 qa[2][2];
#pragma unroll
  for (int s = 0; s < 2; s++) {
    const bf16_t* qp = qkv + base + (size_t)(qbase + s * 16 + l15) * LD + h * 64 + lg * 8;
    qa[s][0] = *reinterpret_cast<const bf16x8*>(qp);
    qa[s][1] = *reinterpret_cast<const bf16x8*>(qp + 32);
  }

  const bf16_t* Kb = qkv + base + 1024 + h * 64;
  const bf16_t* Vb = qkv + base + 2048 + h * 64;

  // K staging source (XOR-swizzled chunks), V staging source (pi layout)
  const int krr = lane >> 3;
  const int kcc = (lane & 7) ^ krr;
  const bf16_t* ksrc0 = Kb + (size_t)(wave * 16 + krr) * LD + kcc * 8;
  const bf16_t* ksrc1 = ksrc0 + (size_t)8 * LD;
  const int vd0 = (lane & 1) * 8 + wave * 16;
  const int vkv = ((lane >> 1) & 3) + ((lane >> 3) & 3) * 4 + (lane >> 5) * 16;
  const bf16_t* vsrc0 = Vb + (size_t)vkv * LD + vd0;
  const bf16_t* vsrc1 = vsrc0 + (size_t)32 * LD;

  bf16_t* ksb = &Ks[0][0];
  bf16_t* vsb = &Vs[0][0];
  const char* ksr = (const char*)&Ks[0][0];
  const unsigned vs_byte =
      (unsigned)(size_t)(__attribute__((address_space(3))) void*)(&Vs[0][0]);
  const unsigned tr_lane = vs_byte + lane * 8;

  const int rx7 = l15 & 7;
  const unsigned kb0 = (unsigned)(l15 * 128 + ((lg ^ rx7) << 4));
  const unsigned kb1 = (unsigned)(l15 * 128 + (((4 | lg) ^ rx7) << 4));

  float lr[2] = {0.f, 0.f};
  f32x4 oacc[2][4] = {};

  // stage pair PB at kv offset KV0 (two 64-row tiles), 8 gloads/wave
#define STAGE_PAIR(PB, KV0) do {                                         \
    const size_t _go = (size_t)(KV0) * LD;                               \
    const size_t _g1 = _go + (size_t)64 * LD;                            \
    bf16_t* _kd = ksb + (PB) * 8192 + wave * 1024;                       \
    bf16_t* _vd = vsb + (PB) * 8192 + wave * 1024;                       \
    GLOAD_LDS16(ksrc0 + _go, _kd);                                       \
    GLOAD_LDS16(ksrc1 + _go, _kd + 512);                                 \
    GLOAD_LDS16(ksrc0 + _g1, _kd + 4096);                                \
    GLOAD_LDS16(ksrc1 + _g1, _kd + 4096 + 512);                          \
    GLOAD_LDS16(vsrc0 + _go, _vd);                                       \
    GLOAD_LDS16(vsrc1 + _go, _vd + 512);                                 \
    GLOAD_LDS16(vsrc0 + _g1, _vd + 4096);                                \
    GLOAD_LDS16(vsrc1 + _g1, _vd + 4096 + 512);                          \
  } while (0)

  // softmax for one tile's sacc -> pa fragments + lr
#define SOFTMAX(SACC, PA) do {                                           \
    unsigned _pu[16];                                                    \
    float _l0 = 0.f, _l1 = 0.f;                                          \
    _Pragma("unroll")                                                    \
    for (int tt = 0; tt < 4; tt++) {                                     \
      const float a0 = __builtin_exp2f(SACC[0][tt][0]);                  \
      const float a1 = __builtin_exp2f(SACC[0][tt][1]);                  \
      const float a2 = __builtin_exp2f(SACC[0][tt][2]);                  \
      const float a3 = __builtin_exp2f(SACC[0][tt][3]);                  \
      _l0 += (a0 + a1) + (a2 + a3);                                      \
      _pu[(tt >> 1) * 4 + (tt & 1) * 2 + 0] = pack_bf16_pair(a0, a1);    \
      _pu[(tt >> 1) * 4 + (tt & 1) * 2 + 1] = pack_bf16_pair(a2, a3);    \
      const float b0 = __builtin_exp2f(SACC[1][tt][0]);                  \
      const float b1 = __builtin_exp2f(SACC[1][tt][1]);                  \
      const float b2 = __builtin_exp2f(SACC[1][tt][2]);                  \
      const float b3 = __builtin_exp2f(SACC[1][tt][3]);                  \
      _l1 += (b0 + b1) + (b2 + b3);                                      \
      _pu[8 + (tt >> 1) * 4 + (tt & 1) * 2 + 0] = pack_bf16_pair(b0, b1);\
      _pu[8 + (tt >> 1) * 4 + (tt & 1) * 2 + 1] = pack_bf16_pair(b2, b3);\
    }                                                                    \
    lr[0] += _l0; lr[1] += _l1;                                          \
    PA[0][0] = *reinterpret_cast<bf16x8*>(&_pu[0]);                      \
    PA[0][1] = *reinterpret_cast<bf16x8*>(&_pu[4]);                      \
    PA[1][0] = *reinterpret_cast<bf16x8*>(&_pu[8]);                      \
    PA[1][1] = *reinterpret_cast<bf16x8*>(&_pu[12]);                     \
  } while (0)

  // 16 tr-reads for one tile at byte base TA into named regs
#define TR16(TA, P)                                                      \
  bf16x4 P##l0, P##h0, P##l1, P##h1, P##l2, P##h2, P##l3, P##h3,         \
         P##l4, P##h4, P##l5, P##h5, P##l6, P##h6, P##l7, P##h7;         \
  TRREAD(P##l0, TA, "0");    TRREAD(P##h0, TA, "512");                   \
  TRREAD(P##l1, TA, "1024"); TRREAD(P##h1, TA, "1536");                  \
  TRREAD(P##l2, TA, "2048"); TRREAD(P##h2, TA, "2560");                  \
  TRREAD(P##l3, TA, "3072"); TRREAD(P##h3, TA, "3584");                  \
  TRREAD(P##l4, TA, "4096"); TRREAD(P##h4, TA, "4608");                  \
  TRREAD(P##l5, TA, "5120"); TRREAD(P##h5, TA, "5632");                  \
  TRREAD(P##l6, TA, "6144"); TRREAD(P##h6, TA, "6656");                  \
  TRREAD(P##l7, TA, "7168"); TRREAD(P##h7, TA, "7680");

#define VBUILD(P, VB) do {                                               \
    VB[0][0] = __builtin_shufflevector(P##l0, P##h0, 0,1,2,3,4,5,6,7);   \
    VB[1][0] = __builtin_shufflevector(P##l1, P##h1, 0,1,2,3,4,5,6,7);   \
    VB[0][1] = __builtin_shufflevector(P##l2, P##h2, 0,1,2,3,4,5,6,7);   \
    VB[1][1] = __builtin_shufflevector(P##l3, P##h3, 0,1,2,3,4,5,6,7);   \
    VB[0][2] = __builtin_shufflevector(P##l4, P##h4, 0,1,2,3,4,5,6,7);   \
    VB[1][2] = __builtin_shufflevector(P##l5, P##h5, 0,1,2,3,4,5,6,7);   \
    VB[0][3] = __builtin_shufflevector(P##l6, P##h6, 0,1,2,3,4,5,6,7);   \
    VB[1][3] = __builtin_shufflevector(P##l7, P##h7, 0,1,2,3,4,5,6,7);   \
  } while (0)

#define PV(PA, VB) do { _Pragma("unroll")                                \
    for (int s = 0; s < 2; s++) { _Pragma("unroll")                      \
      for (int dt = 0; dt < 4; dt++) {                                   \
        oacc[s][dt] = MFMA_16x16x32(PA[s][0], VB[0][dt], oacc[s][dt]);   \
        oacc[s][dt] = MFMA_16x16x32(PA[s][1], VB[1][dt], oacc[s][dt]);   \
      } } } while (0)

  // prologue: stage pair 0
  STAGE_PAIR(0, 0);
  __syncthreads();

  for (int j = 0; j < 8; j++) {
    const int pb = j & 1;
    if (j < 7) STAGE_PAIR(pb ^ 1, (j + 1) * 128);

    const unsigned pbyte = (unsigned)pb * 16384;

    // ---- QK tile A (LDS reads + MFMA) ----
    f32x4 sA[2][4] = {};
    {
      const char* kt = ksr + pbyte;
      __builtin_amdgcn_s_setprio(1);
#pragma unroll
      for (int tt = 0; tt < 4; tt++) {
        const bf16x8 k0 = *reinterpret_cast<const bf16x8*>(kt + tt * 2048 + kb0);
        const bf16x8 k1 = *reinterpret_cast<const bf16x8*>(kt + tt * 2048 + kb1);
        sA[0][tt] = MFMA_16x16x32(k0, qa[0][0], sA[0][tt]);
        sA[0][tt] = MFMA_16x16x32(k1, qa[0][1], sA[0][tt]);
        sA[1][tt] = MFMA_16x16x32(k0, qa[1][0], sA[1][tt]);
        sA[1][tt] = MFMA_16x16x32(k1, qa[1][1], sA[1][tt]);
      }
      __builtin_amdgcn_s_setprio(0);
    }

    // ---- issue trA + read K_B fragments; then full drain ----
    const unsigned taA = tr_lane + pbyte;
    TR16(taA, ta_);
    bf16x8 kB[4][2];
    {
      const char* kt = ksr + pbyte + 8192;
#pragma unroll
      for (int tt = 0; tt < 4; tt++) {
        kB[tt][0] = *reinterpret_cast<const bf16x8*>(kt + tt * 2048 + kb0);
        kB[tt][1] = *reinterpret_cast<const bf16x8*>(kt + tt * 2048 + kb1);
      }
    }
    LGKM0;  // trA + kB landed

    // ---- {QK tile B MFMA || softmax A VALU} (compiler interleaves) ----
    f32x4 sB[2][4] = {};
#pragma unroll
    for (int tt = 0; tt < 4; tt++) {
      sB[0][tt] = MFMA_16x16x32(kB[tt][0], qa[0][0], sB[0][tt]);
      sB[0][tt] = MFMA_16x16x32(kB[tt][1], qa[0][1], sB[0][tt]);
      sB[1][tt] = MFMA_16x16x32(kB[tt][0], qa[1][0], sB[1][tt]);
      sB[1][tt] = MFMA_16x16x32(kB[tt][1], qa[1][1], sB[1][tt]);
    }
    bf16x8 paA[2][2];
    SOFTMAX(sA, paA);

    // ---- issue trB ----
    const unsigned taB = taA + 8192;
    TR16(taB, tb_);

    // ---- {PV tile A || softmax B} ----
    bf16x8 vbA[2][4];
    VBUILD(ta_, vbA);
    PV(paA, vbA);
    bf16x8 paB[2][2];
    SOFTMAX(sB, paB);

    LGKM0;  // trB landed

    // ---- PV tile B ----
    bf16x8 vbB[2][4];
    VBUILD(tb_, vbB);
    __builtin_amdgcn_s_setprio(1);
    PV(paB, vbB);
    __builtin_amdgcn_s_setprio(0);

    __syncthreads();  // implicit vmcnt(0): pair j+1 staged; all reads done
  }

#pragma unroll
  for (int s = 0; s < 2; s++) {
    float v = lr[s];
    v += __shfl_xor(v, 16);
    v += __shfl_xor(v, 32);
#pragma unroll
    for (int r = 0; r < 4; r++) {
      const float inv = 1.0f / __shfl(v, lg * 4 + r);
      const size_t row = (size_t)(b * 1024 + qbase + s * 16 + lg * 4 + r);
#pragma unroll
      for (int dt = 0; dt < 4; dt++)
        ctx[row * 1024 + h * 64 + dt * 16 + l15] = (bf16_t)(oacc[s][dt][r] * inv);
    }
  }
#undef STAGE_PAIR
#undef SOFTMAX
#undef TR16
#undef VBUILD
#undef PV
}

extern "C" void kernel_launch(void* const* d_in, const int* in_sizes, int n_in,
                              void* d_out, int out_size, void* d_ws, size_t ws_size,
                              hipStream_t stream) {
  (void)in_sizes; (void)n_in; (void)out_size; (void)ws_size;
  const float* x = (const float*)d_in[0];
  const float* w_qkv = (const float*)d_in[1];
  const float* w_out = (const float*)d_in[2];
  float* out = (float*)d_out;
  char* ws = (char*)d_ws;

  bf16_t* x_b   = (bf16_t*)(ws);                        // 16 MB
  bf16_t* qkv_b = (bf16_t*)(ws + (size_t)(16 << 20));   // 48 MB
  bf16_t* wqT   = (bf16_t*)(ws + (size_t)(64 << 20));   // 6 MB
  bf16_t* woT   = (bf16_t*)(ws + (size_t)(70 << 20));   // 2 MB
  bf16_t* ctx_b = (bf16_t*)(ws + (size_t)(72 << 20));   // 16 MB

  const float qsc = 0.045084220027780106f;  // log2(e)/32

  cvt_kernel<<<8388608 / 8 / 256, 256, 0, stream>>>(x, x_b, 8388608 / 8);
  tcvt_kernel<<<dim3(3072 / 32, 1024 / 32), 256, 0, stream>>>(w_qkv, wqT, 1024, 3072);
  tcvt_kernel<<<dim3(1024 / 32, 1024 / 32), 256, 0, stream>>>(w_out, woT, 1024, 1024);

  gemm_qkv_256<<<384, 512, 131072, stream>>>(x_b, wqT, qkv_b, qsc);
  attn_kernel<<<1024, 256, 0, stream>>>(qkv_b, ctx_b);
  gemm_bt_kernel<float><<<dim3(1024 / 128, 8192 / 128), 256, 0, stream>>>(
      ctx_b, woT, out, 8192, 1024, 1024, 0, 1.0f);
}

// Round 11
// 168.049 us; speedup vs baseline: 1.0473x; 1.0473x over previous
//
#include <hip/hip_runtime.h>
#include <hip/hip_bf16.h>

typedef __bf16 bf16_t;
typedef __bf16 bf16x8 __attribute__((ext_vector_type(8)));
typedef __bf16 bf16x4 __attribute__((ext_vector_type(4)));
typedef float f32x4 __attribute__((ext_vector_type(4)));

constexpr int LD = 3072;

#define MFMA_16x16x32(a, b, c) __builtin_amdgcn_mfma_f32_16x16x32_bf16((a), (b), (c), 0, 0, 0)

#define GLOAD_LDS16(g, l)                                               \
  __builtin_amdgcn_global_load_lds(                                     \
      (const __attribute__((address_space(1))) void*)(g),               \
      (__attribute__((address_space(3))) void*)(l), 16, 0, 0)

#define TRREAD(dst, addr, imm) \
  asm volatile("ds_read_b64_tr_b16 %0, %1 offset:" imm : "=v"(dst) : "v"(addr))

#define BAR __builtin_amdgcn_s_barrier()
#define LGKM0 do { asm volatile("s_waitcnt lgkmcnt(0)" ::: "memory"); \
                   __builtin_amdgcn_sched_barrier(0); } while (0)

// ---------------- fp32 -> bf16 convert (16B-store vectorized) ----------------
__global__ void cvt_kernel(const float* __restrict__ in, bf16_t* __restrict__ out, int n8) {
  int i = blockIdx.x * blockDim.x + threadIdx.x;
  if (i >= n8) return;
  const float4 a = reinterpret_cast<const float4*>(in)[2 * i];
  const float4 c = reinterpret_cast<const float4*>(in)[2 * i + 1];
  bf16x8 o;
  o[0] = (bf16_t)a.x; o[1] = (bf16_t)a.y; o[2] = (bf16_t)a.z; o[3] = (bf16_t)a.w;
  o[4] = (bf16_t)c.x; o[5] = (bf16_t)c.y; o[6] = (bf16_t)c.z; o[7] = (bf16_t)c.w;
  reinterpret_cast<bf16x8*>(out)[i] = o;
}

// ------------- transpose + convert: out[c][r] = (bf16) in[r][c] -------------
__global__ void tcvt_kernel(const float* __restrict__ in, bf16_t* __restrict__ out, int R, int C) {
  __shared__ float tile[32][33];
  const int c0 = blockIdx.x * 32, r0 = blockIdx.y * 32;
  const int tx = threadIdx.x & 31, ty = threadIdx.x >> 5;  // 32 x 8
#pragma unroll
  for (int i = 0; i < 32; i += 8)
    tile[ty + i][tx] = in[(size_t)(r0 + ty + i) * C + (c0 + tx)];
  __syncthreads();
#pragma unroll
  for (int i = 0; i < 32; i += 8)
    out[(size_t)(c0 + ty + i) * R + (r0 + tx)] = (bf16_t)tile[tx][ty + i];
}

// ------- GEMM 128x256-tile, 4-phase, triple-buffered, counted vmcnt -------
// C[M][N] = A[M][1024] * Bt[N][1024]^T. 512 thr = 8 waves (2M x 4N),
// per-wave 64x64 out (acc[4][4]). K-tile 64. LDS: A 3x16KB + B 3x32KB = 144KB.
// Stage slots per K-tile: {A, Bh0} in ph1, {Bh1} in ph2 (6 gloads/thread),
// staged 2 tiles ahead into buf (bc+2)%3. vmcnt(6) at tile end drains tile
// T+1's 6 loads (oldest), keeps T+2's 6 in flight. WAR: buf (bc+2)%3 is tile
// T-1's buf, whose ds_reads completed before T-1's closing barrier.
// XOR chunk-swizzle (chunk ^= row&7) pre-applied on global source (rule #21).
template <typename OutT>
__global__ __launch_bounds__(512, 1) void gemm_bt_128x256(
    const bf16_t* __restrict__ A, const bf16_t* __restrict__ Bt,
    OutT* __restrict__ C, int N, int nrowblk, int q_cols, float q_scale) {
  constexpr int K = 1024;
  extern __shared__ char smem[];
  char* asB = smem;            // 3 x 16 KB : A [buf][128][64]
  char* bsB = smem + 49152;    // 3 x 32 KB : B [buf][2half][128][64]

  const int t = threadIdx.x;
  const int lane = t & 63, wave = t >> 6;
  const int l15 = lane & 15, lg = lane >> 4;
  const int wr = wave >> 2, wc = wave & 3;

  const int cpx = (int)gridDim.x >> 3;  // nwg divisible by 8
  const int bid = blockIdx.x;
  const int wg = (bid & 7) * cpx + (bid >> 3);
  const int brow = (wg % nrowblk) * 128;
  const int bcol = (wg / nrowblk) * 256;

  const int srow = t >> 3;
  const int schk = (t & 7) ^ (srow & 7);
  const bf16_t* aS = A + (size_t)(brow + srow) * K + schk * 8;
  const bf16_t* bS = Bt + (size_t)(bcol + srow) * K + schk * 8;
  const int ldst = t * 8;

#define STG_A(T, BUF) do {                                               \
    const bf16_t* _s = aS + (T) * 64;                                    \
    bf16_t* _d = (bf16_t*)(asB + (BUF) * 16384) + ldst;                  \
    GLOAD_LDS16(_s, _d);                                                 \
    GLOAD_LDS16(_s + (size_t)64 * K, _d + 4096);                         \
  } while (0)
#define STG_B(T, H, BUF) do {                                            \
    const bf16_t* _s = bS + (size_t)((H) * 128) * K + (T) * 64;          \
    bf16_t* _d = (bf16_t*)(bsB + (BUF) * 32768 + (H) * 16384) + ldst;    \
    GLOAD_LDS16(_s, _d);                                                 \
    GLOAD_LDS16(_s + (size_t)64 * K, _d + 4096);                         \
  } while (0)

  const int rx = l15 & 7;
  const unsigned c0 = ((unsigned)(lg ^ rx)) << 4;
  const unsigned c1 = ((unsigned)((4 | lg) ^ rx)) << 4;
  const unsigned a_rd = (unsigned)(wr * 8192 + l15 * 128);
  const unsigned b_rd = (unsigned)((wc >> 1) * 16384 + (wc & 1) * 8192 + l15 * 128);

  f32x4 acc[4][4] = {};
  bf16x8 af[2][2], bfr[4][2];

#define RD_AF(BUF, MH) do { _Pragma("unroll")                            \
    for (int m = 0; m < 2; ++m) {                                        \
      const char* _p = asB + (BUF) * 16384 + a_rd + ((MH) * 2 + m) * 2048; \
      af[m][0] = *(const bf16x8*)(_p + c0);                              \
      af[m][1] = *(const bf16x8*)(_p + c1); } } while (0)
#define RD_BF(BUF) do { _Pragma("unroll")                                \
    for (int n = 0; n < 4; ++n) {                                        \
      const char* _p = bsB + (BUF) * 32768 + b_rd + n * 2048;            \
      bfr[n][0] = *(const bf16x8*)(_p + c0);                             \
      bfr[n][1] = *(const bf16x8*)(_p + c1); } } while (0)
#define MM(MH) do {                                                      \
    __builtin_amdgcn_s_setprio(1);                                       \
    _Pragma("unroll")                                                    \
    for (int m = 0; m < 2; ++m) { _Pragma("unroll")                      \
      for (int n = 0; n < 4; ++n) {                                      \
        acc[(MH)*2+m][n] =                                               \
            MFMA_16x16x32(af[m][0], bfr[n][0], acc[(MH)*2+m][n]);        \
        acc[(MH)*2+m][n] =                                               \
            MFMA_16x16x32(af[m][1], bfr[n][1], acc[(MH)*2+m][n]); } }    \
    __builtin_amdgcn_s_setprio(0); } while (0)

  // prologue: T0 -> buf0 (6 loads), T1 -> buf1 (6 loads); drain T0 only
  STG_A(0, 0); STG_B(0, 0, 0); STG_B(0, 1, 0);
  STG_A(1, 1); STG_B(1, 0, 1); STG_B(1, 1, 1);
  asm volatile("s_waitcnt vmcnt(6)" ::: "memory");
  BAR;

  int bc = 0;
  for (int T = 0; T < 16; ++T) {
    const bool pf = (T + 2 < 16);
    const int bs = (bc >= 1) ? (bc - 1) : 2;  // (bc+2)%3 == tile T-1's buf
    // ---- ph1: quadrant MH0 ----
    if (pf) { STG_A(T + 2, bs); STG_B(T + 2, 0, bs); }
    RD_AF(bc, 0);
    RD_BF(bc);
    BAR; LGKM0; MM(0); BAR;
    // ---- ph2: quadrant MH1 (B-frags held in regs) ----
    if (pf) STG_B(T + 2, 1, bs);
    RD_AF(bc, 1);
    BAR; LGKM0; MM(1);
    if (pf) asm volatile("s_waitcnt vmcnt(6)" ::: "memory");
    else    asm volatile("s_waitcnt vmcnt(0)" ::: "memory");
    BAR;
    bc = (bc == 2) ? 0 : bc + 1;
  }

  const float sc = (bcol < q_cols) ? q_scale : 1.0f;  // block-uniform
  const int crow0 = brow + wr * 64 + lg * 4;
  const int ccol0 = bcol + wc * 64 + l15;
#pragma unroll
  for (int m = 0; m < 4; ++m)
#pragma unroll
    for (int n = 0; n < 4; ++n)
#pragma unroll
      for (int r = 0; r < 4; ++r)
        C[(size_t)(crow0 + m * 16 + r) * N + ccol0 + n * 16] =
            (OutT)(acc[m][n][r] * sc);
#undef STG_A
#undef STG_B
#undef RD_AF
#undef RD_BF
#undef MM
}

// ------------- fused attention (v8, reverted to R9 exactly) -------------
__device__ __forceinline__ unsigned pack_bf16_pair(float a, float b) {
  union { __hip_bfloat162 h; unsigned u; } c;
  c.h = __float22bfloat162_rn(float2{a, b});  // v_cvt_pk_bf16_f32
  return c.u;
}

__global__ __launch_bounds__(256, 3) void attn_kernel(const bf16_t* __restrict__ qkv,
                                                      bf16_t* __restrict__ ctx) {
  __shared__ bf16_t Ks[2][4096];  // swizzled K, double-buffered (16 KB)
  __shared__ bf16_t Vs[2][4096];  // pi-subtiled V, double-buffered (16 KB)
  const int tid = threadIdx.x, lane = tid & 63, wave = tid >> 6;
  const int l15 = lane & 15, lg = (lane >> 4) & 3;
  const int flat = blockIdx.x;
  const int xcd = flat & 7, rr = flat >> 3;
  const int qt = rr & 7;
  const int hb = xcd * 16 + (rr >> 3);
  const int h = hb & 15, b = hb >> 4;
  const size_t base = (size_t)b * 1024 * LD;
  const int qbase = qt * 128 + wave * 32;

  bf16x8 qa[2][2];
#pragma unroll
  for (int s = 0; s < 2; s++) {
    const bf16_t* qp = qkv + base + (size_t)(qbase + s * 16 + l15) * LD + h * 64 + lg * 8;
    qa[s][0] = *reinterpret_cast<const bf16x8*>(qp);
    qa[s][1] = *reinterpret_cast<const bf16x8*>(qp + 32);
  }

  const bf16_t* Kb = qkv + base + 1024 + h * 64;
  const bf16_t* Vb = qkv + base + 2048 + h * 64;

  const int krr = lane >> 3;
  const int kcc = (lane & 7) ^ krr;
  const bf16_t* ksrc0 = Kb + (size_t)(wave * 16 + krr) * LD + kcc * 8;
  const bf16_t* ksrc1 = ksrc0 + (size_t)8 * LD;

  const int vd0 = (lane & 1) * 8 + wave * 16;
  const int vkv = ((lane >> 1) & 3) + ((lane >> 3) & 3) * 4 + (lane >> 5) * 16;
  const bf16_t* vsrc0 = Vb + (size_t)vkv * LD + vd0;
  const bf16_t* vsrc1 = vsrc0 + (size_t)32 * LD;

  bf16_t* ksb = &Ks[0][0];
  bf16_t* vsb = &Vs[0][0];
  const char* ksr = (const char*)&Ks[0][0];
  const unsigned vs_byte =
      (unsigned)(size_t)(__attribute__((address_space(3))) void*)(&Vs[0][0]);
  const unsigned tr_lane = vs_byte + lane * 8;

  const int rx7 = l15 & 7;
  const unsigned kb0 = (unsigned)(l15 * 128 + ((lg ^ rx7) << 4));
  const unsigned kb1 = (unsigned)(l15 * 128 + (((4 | lg) ^ rx7) << 4));

  float lr[2] = {0.f, 0.f};
  f32x4 oacc[2][4] = {};

  GLOAD_LDS16(ksrc0, ksb + wave * 1024);
  GLOAD_LDS16(ksrc1, ksb + wave * 1024 + 512);
  GLOAD_LDS16(vsrc0, vsb + wave * 1024);
  GLOAD_LDS16(vsrc1, vsb + wave * 1024 + 512);
  ksrc0 += (size_t)64 * LD; ksrc1 += (size_t)64 * LD;
  vsrc0 += (size_t)64 * LD; vsrc1 += (size_t)64 * LD;
  __syncthreads();

  for (int t = 0; t < 16; t++) {
    const int cur = t & 1;
    if (t < 15) {
      bf16_t* kd = ksb + (cur ^ 1) * 4096 + wave * 1024;
      bf16_t* vd = vsb + (cur ^ 1) * 4096 + wave * 1024;
      GLOAD_LDS16(ksrc0, kd);
      GLOAD_LDS16(ksrc1, kd + 512);
      GLOAD_LDS16(vsrc0, vd);
      GLOAD_LDS16(vsrc1, vd + 512);
      ksrc0 += (size_t)64 * LD; ksrc1 += (size_t)64 * LD;
      vsrc0 += (size_t)64 * LD; vsrc1 += (size_t)64 * LD;
    }

    f32x4 sacc[2][4] = {};
    const char* kt = ksr + cur * 8192;
    __builtin_amdgcn_s_setprio(1);
#pragma unroll
    for (int tt = 0; tt < 4; tt++) {
      const bf16x8 k0 = *reinterpret_cast<const bf16x8*>(kt + tt * 2048 + kb0);
      const bf16x8 k1 = *reinterpret_cast<const bf16x8*>(kt + tt * 2048 + kb1);
      sacc[0][tt] = MFMA_16x16x32(k0, qa[0][0], sacc[0][tt]);
      sacc[0][tt] = MFMA_16x16x32(k1, qa[0][1], sacc[0][tt]);
      sacc[1][tt] = MFMA_16x16x32(k0, qa[1][0], sacc[1][tt]);
      sacc[1][tt] = MFMA_16x16x32(k1, qa[1][1], sacc[1][tt]);
    }
    __builtin_amdgcn_s_setprio(0);

    const unsigned ta = tr_lane + (unsigned)cur * 8192;
    bf16x4 tl0, th0, tl2, th2, tl4, th4, tl6, th6;
    TRREAD(tl0, ta, "0");    TRREAD(th0, ta, "512");
    TRREAD(tl2, ta, "2048"); TRREAD(th2, ta, "2560");
    TRREAD(tl4, ta, "4096"); TRREAD(th4, ta, "4608");
    TRREAD(tl6, ta, "6144"); TRREAD(th6, ta, "6656");
    __builtin_amdgcn_sched_barrier(0);

    unsigned pu[16];
    float ls0 = 0.f, ls1 = 0.f;
#pragma unroll
    for (int tt = 0; tt < 4; tt++) {
      const float a0 = __builtin_exp2f(sacc[0][tt][0]);
      const float a1 = __builtin_exp2f(sacc[0][tt][1]);
      const float a2 = __builtin_exp2f(sacc[0][tt][2]);
      const float a3 = __builtin_exp2f(sacc[0][tt][3]);
      ls0 += (a0 + a1) + (a2 + a3);
      pu[(tt >> 1) * 4 + (tt & 1) * 2 + 0] = pack_bf16_pair(a0, a1);
      pu[(tt >> 1) * 4 + (tt & 1) * 2 + 1] = pack_bf16_pair(a2, a3);
      const float b0 = __builtin_exp2f(sacc[1][tt][0]);
      const float b1 = __builtin_exp2f(sacc[1][tt][1]);
      const float b2 = __builtin_exp2f(sacc[1][tt][2]);
      const float b3 = __builtin_exp2f(sacc[1][tt][3]);
      ls1 += (b0 + b1) + (b2 + b3);
      pu[8 + (tt >> 1) * 4 + (tt & 1) * 2 + 0] = pack_bf16_pair(b0, b1);
      pu[8 + (tt >> 1) * 4 + (tt & 1) * 2 + 1] = pack_bf16_pair(b2, b3);
    }
    lr[0] += ls0;
    lr[1] += ls1;
    bf16x8 pa[2][2];
    pa[0][0] = *reinterpret_cast<bf16x8*>(&pu[0]);
    pa[0][1] = *reinterpret_cast<bf16x8*>(&pu[4]);
    pa[1][0] = *reinterpret_cast<bf16x8*>(&pu[8]);
    pa[1][1] = *reinterpret_cast<bf16x8*>(&pu[12]);

    bf16x4 tl1, th1, tl3, th3, tl5, th5, tl7, th7;
    TRREAD(tl1, ta, "1024"); TRREAD(th1, ta, "1536");
    TRREAD(tl3, ta, "3072"); TRREAD(th3, ta, "3584");
    TRREAD(tl5, ta, "5120"); TRREAD(th5, ta, "5632");
    TRREAD(tl7, ta, "7168"); TRREAD(th7, ta, "7680");

    asm volatile("s_waitcnt lgkmcnt(8)" ::: "memory");
    __builtin_amdgcn_sched_barrier(0);
    {
      bf16x8 vb0[4];
      vb0[0] = __builtin_shufflevector(tl0, th0, 0, 1, 2, 3, 4, 5, 6, 7);
      vb0[1] = __builtin_shufflevector(tl2, th2, 0, 1, 2, 3, 4, 5, 6, 7);
      vb0[2] = __builtin_shufflevector(tl4, th4, 0, 1, 2, 3, 4, 5, 6, 7);
      vb0[3] = __builtin_shufflevector(tl6, th6, 0, 1, 2, 3, 4, 5, 6, 7);
      __builtin_amdgcn_s_setprio(1);
#pragma unroll
      for (int s = 0; s < 2; s++)
#pragma unroll
        for (int dt = 0; dt < 4; dt++)
          oacc[s][dt] = MFMA_16x16x32(pa[s][0], vb0[dt], oacc[s][dt]);
      __builtin_amdgcn_s_setprio(0);
    }

    asm volatile("s_waitcnt lgkmcnt(0)" ::: "memory");
    __builtin_amdgcn_sched_barrier(0);
    {
      bf16x8 vb1[4];
      vb1[0] = __builtin_shufflevector(tl1, th1, 0, 1, 2, 3, 4, 5, 6, 7);
      vb1[1] = __builtin_shufflevector(tl3, th3, 0, 1, 2, 3, 4, 5, 6, 7);
      vb1[2] = __builtin_shufflevector(tl5, th5, 0, 1, 2, 3, 4, 5, 6, 7);
      vb1[3] = __builtin_shufflevector(tl7, th7, 0, 1, 2, 3, 4, 5, 6, 7);
      __builtin_amdgcn_s_setprio(1);
#pragma unroll
      for (int s = 0; s < 2; s++)
#pragma unroll
        for (int dt = 0; dt < 4; dt++)
          oacc[s][dt] = MFMA_16x16x32(pa[s][1], vb1[dt], oacc[s][dt]);
      __builtin_amdgcn_s_setprio(0);
    }

    __syncthreads();
  }

#pragma unroll
  for (int s = 0; s < 2; s++) {
    float v = lr[s];
    v += __shfl_xor(v, 16);
    v += __shfl_xor(v, 32);
#pragma unroll
    for (int r = 0; r < 4; r++) {
      const float inv = 1.0f / __shfl(v, lg * 4 + r);
      const size_t row = (size_t)(b * 1024 + qbase + s * 16 + lg * 4 + r);
#pragma unroll
      for (int dt = 0; dt < 4; dt++)
        ctx[row * 1024 + h * 64 + dt * 16 + l15] = (bf16_t)(oacc[s][dt][r] * inv);
    }
  }
}

extern "C" void kernel_launch(void* const* d_in, const int* in_sizes, int n_in,
                              void* d_out, int out_size, void* d_ws, size_t ws_size,
                              hipStream_t stream) {
  (void)in_sizes; (void)n_in; (void)out_size; (void)ws_size;
  const float* x = (const float*)d_in[0];
  const float* w_qkv = (const float*)d_in[1];
  const float* w_out = (const float*)d_in[2];
  float* out = (float*)d_out;
  char* ws = (char*)d_ws;

  bf16_t* x_b   = (bf16_t*)(ws);                        // 16 MB
  bf16_t* qkv_b = (bf16_t*)(ws + (size_t)(16 << 20));   // 48 MB
  bf16_t* wqT   = (bf16_t*)(ws + (size_t)(64 << 20));   // 6 MB
  bf16_t* woT   = (bf16_t*)(ws + (size_t)(70 << 20));   // 2 MB
  bf16_t* ctx_b = (bf16_t*)(ws + (size_t)(72 << 20));   // 16 MB

  const float qsc = 0.045084220027780106f;  // log2(e)/32

  cvt_kernel<<<8388608 / 8 / 256, 256, 0, stream>>>(x, x_b, 8388608 / 8);
  tcvt_kernel<<<dim3(3072 / 32, 1024 / 32), 256, 0, stream>>>(w_qkv, wqT, 1024, 3072);
  tcvt_kernel<<<dim3(1024 / 32, 1024 / 32), 256, 0, stream>>>(w_out, woT, 1024, 1024);

  // gemm1: M=8192 N=3072 -> grid 64x12 = 768 (exactly 3 rounds of 256 CUs)
  gemm_bt_128x256<bf16_t><<<768, 512, 147456, stream>>>(
      x_b, wqT, qkv_b, 3072, 64, 1024, qsc);
  attn_kernel<<<1024, 256, 0, stream>>>(qkv_b, ctx_b);
  // gemm2: M=8192 N=1024 -> grid 64x4 = 256 (exactly 1 round)
  gemm_bt_128x256<float><<<256, 512, 147456, stream>>>(
      ctx_b, woT, out, 1024, 64, 0, 1.0f);
}

// Round 12
// 161.603 us; speedup vs baseline: 1.0891x; 1.0399x over previous
//
#include <hip/hip_runtime.h>
#include <hip/hip_bf16.h>

typedef __bf16 bf16_t;
typedef __bf16 bf16x8 __attribute__((ext_vector_type(8)));
typedef __bf16 bf16x4 __attribute__((ext_vector_type(4)));
typedef float f32x4 __attribute__((ext_vector_type(4)));

constexpr int LD = 3072;

#define MFMA_16x16x32(a, b, c) __builtin_amdgcn_mfma_f32_16x16x32_bf16((a), (b), (c), 0, 0, 0)

#define GLOAD_LDS16(g, l)                                               \
  __builtin_amdgcn_global_load_lds(                                     \
      (const __attribute__((address_space(1))) void*)(g),               \
      (__attribute__((address_space(3))) void*)(l), 16, 0, 0)

#define TRREAD(dst, addr, imm) \
  asm volatile("ds_read_b64_tr_b16 %0, %1 offset:" imm : "=v"(dst) : "v"(addr))

#define BAR __builtin_amdgcn_s_barrier()
#define LGKM0 do { asm volatile("s_waitcnt lgkmcnt(0)" ::: "memory"); \
                   __builtin_amdgcn_sched_barrier(0); } while (0)

// ---------------- fp32 -> bf16 convert (16B-store vectorized) ----------------
__global__ void cvt_kernel(const float* __restrict__ in, bf16_t* __restrict__ out, int n8) {
  int i = blockIdx.x * blockDim.x + threadIdx.x;
  if (i >= n8) return;
  const float4 a = reinterpret_cast<const float4*>(in)[2 * i];
  const float4 c = reinterpret_cast<const float4*>(in)[2 * i + 1];
  bf16x8 o;
  o[0] = (bf16_t)a.x; o[1] = (bf16_t)a.y; o[2] = (bf16_t)a.z; o[3] = (bf16_t)a.w;
  o[4] = (bf16_t)c.x; o[5] = (bf16_t)c.y; o[6] = (bf16_t)c.z; o[7] = (bf16_t)c.w;
  reinterpret_cast<bf16x8*>(out)[i] = o;
}

// ------------- transpose + convert: out[c][r] = (bf16) in[r][c] -------------
__global__ void tcvt_kernel(const float* __restrict__ in, bf16_t* __restrict__ out, int R, int C) {
  __shared__ float tile[32][33];
  const int c0 = blockIdx.x * 32, r0 = blockIdx.y * 32;
  const int tx = threadIdx.x & 31, ty = threadIdx.x >> 5;  // 32 x 8
#pragma unroll
  for (int i = 0; i < 32; i += 8)
    tile[ty + i][tx] = in[(size_t)(r0 + ty + i) * C + (c0 + tx)];
  __syncthreads();
#pragma unroll
  for (int i = 0; i < 32; i += 8)
    out[(size_t)(c0 + ty + i) * R + (r0 + tx)] = (bf16_t)tile[tx][ty + i];
}

// ------------- GEMM1 (QKV): 256x256 tile, 8-phase, counted vmcnt (R9) -------
__global__ __launch_bounds__(512, 2) void gemm_qkv_256(
    const bf16_t* __restrict__ A, const bf16_t* __restrict__ Bt,
    bf16_t* __restrict__ C, float q_scale) {
  constexpr int K = 1024;
  extern __shared__ char smem[];
  char* asB = smem;           // 64 KB: A [2][2][128][64]
  char* bsB = smem + 65536;   // 64 KB: B

  const int t = threadIdx.x;
  const int lane = t & 63, wave = t >> 6;
  const int l15 = lane & 15, lg = lane >> 4;
  const int wr = wave >> 2, wc = wave & 3;

  const int bid = blockIdx.x;
  const int wg = (bid & 7) * 48 + (bid >> 3);
  const int brow = (wg & 31) * 256;
  const int bcol = (wg >> 5) * 256;

  const int srow = t >> 3;
  const int schk = (t & 7) ^ (srow & 7);
  const bf16_t* aS = A + (size_t)(brow + srow) * K + schk * 8;
  const bf16_t* bS = Bt + (size_t)(bcol + srow) * K + schk * 8;
  const int ldst = t * 8;

#define STG_A(T, H) do {                                                      \
    const bf16_t* _s = aS + (size_t)((H) * 128) * K + (T) * 64;               \
    bf16_t* _d = (bf16_t*)(asB + ((T) & 1) * 32768 + (H) * 16384) + ldst;     \
    GLOAD_LDS16(_s, _d);                                                      \
    GLOAD_LDS16(_s + (size_t)64 * K, _d + 4096);                              \
  } while (0)
#define STG_B(T, H) do {                                                      \
    const bf16_t* _s = bS + (size_t)((H) * 128) * K + (T) * 64;               \
    bf16_t* _d = (bf16_t*)(bsB + ((T) & 1) * 32768 + (H) * 16384) + ldst;     \
    GLOAD_LDS16(_s, _d);                                                      \
    GLOAD_LDS16(_s + (size_t)64 * K, _d + 4096);                              \
  } while (0)

  const int rx = l15 & 7;
  const unsigned c0 = ((unsigned)(lg ^ rx)) << 4;
  const unsigned c1 = ((unsigned)((4 | lg) ^ rx)) << 4;
  const unsigned a_rd = (unsigned)(wr * 16384 + l15 * 128);
  const unsigned b_rd = (unsigned)((wc >> 1) * 16384 + (wc & 1) * 8192 + l15 * 128);

  f32x4 acc[8][4] = {};
  bf16x8 af[4][2], bfr[2][2];

#define RD_AF(BUF, MH) do { _Pragma("unroll")                                 \
    for (int m = 0; m < 4; ++m) {                                             \
      const char* _p = asB + (BUF) * 32768 + a_rd + ((MH) * 4 + m) * 2048;    \
      af[m][0] = *(const bf16x8*)(_p + c0);                                   \
      af[m][1] = *(const bf16x8*)(_p + c1); } } while (0)
#define RD_BF(BUF, NH) do { _Pragma("unroll")                                 \
    for (int n = 0; n < 2; ++n) {                                             \
      const char* _p = bsB + (BUF) * 32768 + b_rd + ((NH) * 2 + n) * 2048;    \
      bfr[n][0] = *(const bf16x8*)(_p + c0);                                  \
      bfr[n][1] = *(const bf16x8*)(_p + c1); } } while (0)
#define MM16(MH, NH) do {                                                     \
    __builtin_amdgcn_s_setprio(1);                                            \
    _Pragma("unroll")                                                         \
    for (int m = 0; m < 4; ++m) { _Pragma("unroll")                           \
      for (int n = 0; n < 2; ++n) {                                           \
        acc[(MH)*4+m][(NH)*2+n] =                                             \
            MFMA_16x16x32(af[m][0], bfr[n][0], acc[(MH)*4+m][(NH)*2+n]);      \
        acc[(MH)*4+m][(NH)*2+n] =                                             \
            MFMA_16x16x32(af[m][1], bfr[n][1], acc[(MH)*4+m][(NH)*2+n]); } }  \
    __builtin_amdgcn_s_setprio(0); } while (0)

  STG_A(0, 0); STG_A(0, 1); STG_B(0, 0); STG_B(0, 1); STG_A(1, 0);
  asm volatile("s_waitcnt vmcnt(2)" ::: "memory");
  BAR;

  for (int i = 0; i < 8; ++i) {
    const int T1 = 2 * i + 1, T2 = 2 * i + 2, T3 = 2 * i + 3;
    const bool pf = (i < 7);
    STG_A(T1, 1);
    RD_AF(0, 0); RD_BF(0, 0);
    BAR; LGKM0; MM16(0, 0); BAR;
    STG_B(T1, 0);
    RD_BF(0, 1);
    BAR; LGKM0; MM16(0, 1); BAR;
    STG_B(T1, 1);
    RD_AF(0, 1);
    BAR; LGKM0; MM16(1, 1); BAR;
    if (pf) STG_A(T2, 0);
    RD_BF(0, 0);
    BAR; LGKM0; MM16(1, 0);
    if (pf) asm volatile("s_waitcnt vmcnt(2)" ::: "memory");
    else    asm volatile("s_waitcnt vmcnt(0)" ::: "memory");
    BAR;
    if (pf) STG_A(T2, 1);
    RD_AF(1, 0); RD_BF(1, 0);
    BAR; LGKM0; MM16(0, 0); BAR;
    if (pf) STG_B(T2, 0);
    RD_BF(1, 1);
    BAR; LGKM0; MM16(0, 1); BAR;
    if (pf) STG_B(T2, 1);
    RD_AF(1, 1);
    BAR; LGKM0; MM16(1, 1); BAR;
    if (pf) STG_A(T3, 0);
    RD_BF(1, 0);
    BAR; LGKM0; MM16(1, 0);
    asm volatile("s_waitcnt vmcnt(2)" ::: "memory");
    BAR;
  }

  const float sc = (bcol < 1024) ? q_scale : 1.0f;
  const int crow0 = brow + wr * 128 + lg * 4;
  const int ccol0 = bcol + wc * 64 + l15;
#pragma unroll
  for (int m = 0; m < 8; ++m)
#pragma unroll
    for (int n = 0; n < 4; ++n)
#pragma unroll
      for (int r = 0; r < 4; ++r)
        C[(size_t)(crow0 + m * 16 + r) * 3072 + ccol0 + n * 16] =
            (bf16_t)(acc[m][n][r] * sc);
#undef STG_A
#undef STG_B
#undef RD_AF
#undef RD_BF
#undef MM16
}

// ------- GEMM2: 128x256-tile, 4-phase, triple-buffered (R11, grid 256) ------
template <typename OutT>
__global__ __launch_bounds__(512, 1) void gemm_bt_128x256(
    const bf16_t* __restrict__ A, const bf16_t* __restrict__ Bt,
    OutT* __restrict__ C, int N, int nrowblk, int q_cols, float q_scale) {
  constexpr int K = 1024;
  extern __shared__ char smem[];
  char* asB = smem;            // 3 x 16 KB : A [buf][128][64]
  char* bsB = smem + 49152;    // 3 x 32 KB : B [buf][2half][128][64]

  const int t = threadIdx.x;
  const int lane = t & 63, wave = t >> 6;
  const int l15 = lane & 15, lg = lane >> 4;
  const int wr = wave >> 2, wc = wave & 3;

  const int cpx = (int)gridDim.x >> 3;
  const int bid = blockIdx.x;
  const int wg = (bid & 7) * cpx + (bid >> 3);
  const int brow = (wg % nrowblk) * 128;
  const int bcol = (wg / nrowblk) * 256;

  const int srow = t >> 3;
  const int schk = (t & 7) ^ (srow & 7);
  const bf16_t* aS = A + (size_t)(brow + srow) * K + schk * 8;
  const bf16_t* bS = Bt + (size_t)(bcol + srow) * K + schk * 8;
  const int ldst = t * 8;

#define STG_A(T, BUF) do {                                               \
    const bf16_t* _s = aS + (T) * 64;                                    \
    bf16_t* _d = (bf16_t*)(asB + (BUF) * 16384) + ldst;                  \
    GLOAD_LDS16(_s, _d);                                                 \
    GLOAD_LDS16(_s + (size_t)64 * K, _d + 4096);                         \
  } while (0)
#define STG_B(T, H, BUF) do {                                            \
    const bf16_t* _s = bS + (size_t)((H) * 128) * K + (T) * 64;          \
    bf16_t* _d = (bf16_t*)(bsB + (BUF) * 32768 + (H) * 16384) + ldst;    \
    GLOAD_LDS16(_s, _d);                                                 \
    GLOAD_LDS16(_s + (size_t)64 * K, _d + 4096);                         \
  } while (0)

  const int rx = l15 & 7;
  const unsigned c0 = ((unsigned)(lg ^ rx)) << 4;
  const unsigned c1 = ((unsigned)((4 | lg) ^ rx)) << 4;
  const unsigned a_rd = (unsigned)(wr * 8192 + l15 * 128);
  const unsigned b_rd = (unsigned)((wc >> 1) * 16384 + (wc & 1) * 8192 + l15 * 128);

  f32x4 acc[4][4] = {};
  bf16x8 af[2][2], bfr[4][2];

#define RD_AF(BUF, MH) do { _Pragma("unroll")                            \
    for (int m = 0; m < 2; ++m) {                                        \
      const char* _p = asB + (BUF) * 16384 + a_rd + ((MH) * 2 + m) * 2048; \
      af[m][0] = *(const bf16x8*)(_p + c0);                              \
      af[m][1] = *(const bf16x8*)(_p + c1); } } while (0)
#define RD_BF(BUF) do { _Pragma("unroll")                                \
    for (int n = 0; n < 4; ++n) {                                        \
      const char* _p = bsB + (BUF) * 32768 + b_rd + n * 2048;            \
      bfr[n][0] = *(const bf16x8*)(_p + c0);                             \
      bfr[n][1] = *(const bf16x8*)(_p + c1); } } while (0)
#define MM(MH) do {                                                      \
    __builtin_amdgcn_s_setprio(1);                                       \
    _Pragma("unroll")                                                    \
    for (int m = 0; m < 2; ++m) { _Pragma("unroll")                      \
      for (int n = 0; n < 4; ++n) {                                      \
        acc[(MH)*2+m][n] =                                               \
            MFMA_16x16x32(af[m][0], bfr[n][0], acc[(MH)*2+m][n]);        \
        acc[(MH)*2+m][n] =                                               \
            MFMA_16x16x32(af[m][1], bfr[n][1], acc[(MH)*2+m][n]); } }    \
    __builtin_amdgcn_s_setprio(0); } while (0)

  STG_A(0, 0); STG_B(0, 0, 0); STG_B(0, 1, 0);
  STG_A(1, 1); STG_B(1, 0, 1); STG_B(1, 1, 1);
  asm volatile("s_waitcnt vmcnt(6)" ::: "memory");
  BAR;

  int bc = 0;
  for (int T = 0; T < 16; ++T) {
    const bool pf = (T + 2 < 16);
    const int bs = (bc >= 1) ? (bc - 1) : 2;
    if (pf) { STG_A(T + 2, bs); STG_B(T + 2, 0, bs); }
    RD_AF(bc, 0);
    RD_BF(bc);
    BAR; LGKM0; MM(0); BAR;
    if (pf) STG_B(T + 2, 1, bs);
    RD_AF(bc, 1);
    BAR; LGKM0; MM(1);
    if (pf) asm volatile("s_waitcnt vmcnt(6)" ::: "memory");
    else    asm volatile("s_waitcnt vmcnt(0)" ::: "memory");
    BAR;
    bc = (bc == 2) ? 0 : bc + 1;
  }

  const float sc = (bcol < q_cols) ? q_scale : 1.0f;
  const int crow0 = brow + wr * 64 + lg * 4;
  const int ccol0 = bcol + wc * 64 + l15;
#pragma unroll
  for (int m = 0; m < 4; ++m)
#pragma unroll
    for (int n = 0; n < 4; ++n)
#pragma unroll
      for (int r = 0; r < 4; ++r)
        C[(size_t)(crow0 + m * 16 + r) * N + ccol0 + n * 16] =
            (OutT)(acc[m][n][r] * sc);
#undef STG_A
#undef STG_B
#undef RD_AF
#undef RD_BF
#undef MM
}

// ------------- fused attention (v10 = v8 + denominator-via-ones-MFMA) -------
// dn[s] += mfma(pa[s][ks], ones): with B=all-ones, out[q][c] = sum_kv P[q][kv].
// C/D row mapping (4*lg+r) == oacc's row mapping, so epilogue needs NO
// cross-lane reduce: inv = 1/dn[s][r] per lane. Removes 32 VALU adds/tile and
// the final shfl_xor reduce; adds 4 MFMA/tile on the 20%-busy matrix pipe.
__device__ __forceinline__ unsigned pack_bf16_pair(float a, float b) {
  union { __hip_bfloat162 h; unsigned u; } c;
  c.h = __float22bfloat162_rn(float2{a, b});  // v_cvt_pk_bf16_f32
  return c.u;
}

__global__ __launch_bounds__(256, 3) void attn_kernel(const bf16_t* __restrict__ qkv,
                                                      bf16_t* __restrict__ ctx) {
  __shared__ bf16_t Ks[2][4096];  // swizzled K, double-buffered (16 KB)
  __shared__ bf16_t Vs[2][4096];  // pi-subtiled V, double-buffered (16 KB)
  const int tid = threadIdx.x, lane = tid & 63, wave = tid >> 6;
  const int l15 = lane & 15, lg = (lane >> 4) & 3;
  const int flat = blockIdx.x;
  const int xcd = flat & 7, rr = flat >> 3;
  const int qt = rr & 7;
  const int hb = xcd * 16 + (rr >> 3);
  const int h = hb & 15, b = hb >> 4;
  const size_t base = (size_t)b * 1024 * LD;
  const int qbase = qt * 128 + wave * 32;

  bf16x8 qa[2][2];
#pragma unroll
  for (int s = 0; s < 2; s++) {
    const bf16_t* qp = qkv + base + (size_t)(qbase + s * 16 + l15) * LD + h * 64 + lg * 8;
    qa[s][0] = *reinterpret_cast<const bf16x8*>(qp);
    qa[s][1] = *reinterpret_cast<const bf16x8*>(qp + 32);
  }

  const bf16_t* Kb = qkv + base + 1024 + h * 64;
  const bf16_t* Vb = qkv + base + 2048 + h * 64;

  const int krr = lane >> 3;
  const int kcc = (lane & 7) ^ krr;
  const bf16_t* ksrc0 = Kb + (size_t)(wave * 16 + krr) * LD + kcc * 8;
  const bf16_t* ksrc1 = ksrc0 + (size_t)8 * LD;

  const int vd0 = (lane & 1) * 8 + wave * 16;
  const int vkv = ((lane >> 1) & 3) + ((lane >> 3) & 3) * 4 + (lane >> 5) * 16;
  const bf16_t* vsrc0 = Vb + (size_t)vkv * LD + vd0;
  const bf16_t* vsrc1 = vsrc0 + (size_t)32 * LD;

  bf16_t* ksb = &Ks[0][0];
  bf16_t* vsb = &Vs[0][0];
  const char* ksr = (const char*)&Ks[0][0];
  const unsigned vs_byte =
      (unsigned)(size_t)(__attribute__((address_space(3))) void*)(&Vs[0][0]);
  const unsigned tr_lane = vs_byte + lane * 8;

  const int rx7 = l15 & 7;
  const unsigned kb0 = (unsigned)(l15 * 128 + ((lg ^ rx7) << 4));
  const unsigned kb1 = (unsigned)(l15 * 128 + (((4 | lg) ^ rx7) << 4));

  bf16x8 ones;
#pragma unroll
  for (int j = 0; j < 8; j++) ones[j] = (bf16_t)1.0f;

  f32x4 dn[2] = {};
  f32x4 oacc[2][4] = {};

  GLOAD_LDS16(ksrc0, ksb + wave * 1024);
  GLOAD_LDS16(ksrc1, ksb + wave * 1024 + 512);
  GLOAD_LDS16(vsrc0, vsb + wave * 1024);
  GLOAD_LDS16(vsrc1, vsb + wave * 1024 + 512);
  ksrc0 += (size_t)64 * LD; ksrc1 += (size_t)64 * LD;
  vsrc0 += (size_t)64 * LD; vsrc1 += (size_t)64 * LD;
  __syncthreads();

  for (int t = 0; t < 16; t++) {
    const int cur = t & 1;
    if (t < 15) {
      bf16_t* kd = ksb + (cur ^ 1) * 4096 + wave * 1024;
      bf16_t* vd = vsb + (cur ^ 1) * 4096 + wave * 1024;
      GLOAD_LDS16(ksrc0, kd);
      GLOAD_LDS16(ksrc1, kd + 512);
      GLOAD_LDS16(vsrc0, vd);
      GLOAD_LDS16(vsrc1, vd + 512);
      ksrc0 += (size_t)64 * LD; ksrc1 += (size_t)64 * LD;
      vsrc0 += (size_t)64 * LD; vsrc1 += (size_t)64 * LD;
    }

    f32x4 sacc[2][4] = {};
    const char* kt = ksr + cur * 8192;
    __builtin_amdgcn_s_setprio(1);
#pragma unroll
    for (int tt = 0; tt < 4; tt++) {
      const bf16x8 k0 = *reinterpret_cast<const bf16x8*>(kt + tt * 2048 + kb0);
      const bf16x8 k1 = *reinterpret_cast<const bf16x8*>(kt + tt * 2048 + kb1);
      sacc[0][tt] = MFMA_16x16x32(k0, qa[0][0], sacc[0][tt]);
      sacc[0][tt] = MFMA_16x16x32(k1, qa[0][1], sacc[0][tt]);
      sacc[1][tt] = MFMA_16x16x32(k0, qa[1][0], sacc[1][tt]);
      sacc[1][tt] = MFMA_16x16x32(k1, qa[1][1], sacc[1][tt]);
    }
    __builtin_amdgcn_s_setprio(0);

    const unsigned ta = tr_lane + (unsigned)cur * 8192;
    bf16x4 tl0, th0, tl2, th2, tl4, th4, tl6, th6;
    TRREAD(tl0, ta, "0");    TRREAD(th0, ta, "512");
    TRREAD(tl2, ta, "2048"); TRREAD(th2, ta, "2560");
    TRREAD(tl4, ta, "4096"); TRREAD(th4, ta, "4608");
    TRREAD(tl6, ta, "6144"); TRREAD(th6, ta, "6656");
    __builtin_amdgcn_sched_barrier(0);

    unsigned pu[16];
#pragma unroll
    for (int tt = 0; tt < 4; tt++) {
      const float a0 = __builtin_exp2f(sacc[0][tt][0]);
      const float a1 = __builtin_exp2f(sacc[0][tt][1]);
      const float a2 = __builtin_exp2f(sacc[0][tt][2]);
      const float a3 = __builtin_exp2f(sacc[0][tt][3]);
      pu[(tt >> 1) * 4 + (tt & 1) * 2 + 0] = pack_bf16_pair(a0, a1);
      pu[(tt >> 1) * 4 + (tt & 1) * 2 + 1] = pack_bf16_pair(a2, a3);
      const float b0 = __builtin_exp2f(sacc[1][tt][0]);
      const float b1 = __builtin_exp2f(sacc[1][tt][1]);
      const float b2 = __builtin_exp2f(sacc[1][tt][2]);
      const float b3 = __builtin_exp2f(sacc[1][tt][3]);
      pu[8 + (tt >> 1) * 4 + (tt & 1) * 2 + 0] = pack_bf16_pair(b0, b1);
      pu[8 + (tt >> 1) * 4 + (tt & 1) * 2 + 1] = pack_bf16_pair(b2, b3);
    }
    bf16x8 pa[2][2];
    pa[0][0] = *reinterpret_cast<bf16x8*>(&pu[0]);
    pa[0][1] = *reinterpret_cast<bf16x8*>(&pu[4]);
    pa[1][0] = *reinterpret_cast<bf16x8*>(&pu[8]);
    pa[1][1] = *reinterpret_cast<bf16x8*>(&pu[12]);

    // denominator rides the matrix pipe (independent of tr-reads)
    dn[0] = MFMA_16x16x32(pa[0][0], ones, dn[0]);
    dn[0] = MFMA_16x16x32(pa[0][1], ones, dn[0]);
    dn[1] = MFMA_16x16x32(pa[1][0], ones, dn[1]);
    dn[1] = MFMA_16x16x32(pa[1][1], ones, dn[1]);

    bf16x4 tl1, th1, tl3, th3, tl5, th5, tl7, th7;
    TRREAD(tl1, ta, "1024"); TRREAD(th1, ta, "1536");
    TRREAD(tl3, ta, "3072"); TRREAD(th3, ta, "3584");
    TRREAD(tl5, ta, "5120"); TRREAD(th5, ta, "5632");
    TRREAD(tl7, ta, "7168"); TRREAD(th7, ta, "7680");

    asm volatile("s_waitcnt lgkmcnt(8)" ::: "memory");
    __builtin_amdgcn_sched_barrier(0);
    {
      bf16x8 vb0[4];
      vb0[0] = __builtin_shufflevector(tl0, th0, 0, 1, 2, 3, 4, 5, 6, 7);
      vb0[1] = __builtin_shufflevector(tl2, th2, 0, 1, 2, 3, 4, 5, 6, 7);
      vb0[2] = __builtin_shufflevector(tl4, th4, 0, 1, 2, 3, 4, 5, 6, 7);
      vb0[3] = __builtin_shufflevector(tl6, th6, 0, 1, 2, 3, 4, 5, 6, 7);
      __builtin_amdgcn_s_setprio(1);
#pragma unroll
      for (int s = 0; s < 2; s++)
#pragma unroll
        for (int dt = 0; dt < 4; dt++)
          oacc[s][dt] = MFMA_16x16x32(pa[s][0], vb0[dt], oacc[s][dt]);
      __builtin_amdgcn_s_setprio(0);
    }

    asm volatile("s_waitcnt lgkmcnt(0)" ::: "memory");
    __builtin_amdgcn_sched_barrier(0);
    {
      bf16x8 vb1[4];
      vb1[0] = __builtin_shufflevector(tl1, th1, 0, 1, 2, 3, 4, 5, 6, 7);
      vb1[1] = __builtin_shufflevector(tl3, th3, 0, 1, 2, 3, 4, 5, 6, 7);
      vb1[2] = __builtin_shufflevector(tl5, th5, 0, 1, 2, 3, 4, 5, 6, 7);
      vb1[3] = __builtin_shufflevector(tl7, th7, 0, 1, 2, 3, 4, 5, 6, 7);
      __builtin_amdgcn_s_setprio(1);
#pragma unroll
      for (int s = 0; s < 2; s++)
#pragma unroll
        for (int dt = 0; dt < 4; dt++)
          oacc[s][dt] = MFMA_16x16x32(pa[s][1], vb1[dt], oacc[s][dt]);
      __builtin_amdgcn_s_setprio(0);
    }

    __syncthreads();
  }

  // ---- epilogue: per-lane denominators (no cross-lane reduce needed) ----
#pragma unroll
  for (int s = 0; s < 2; s++) {
#pragma unroll
    for (int r = 0; r < 4; r++) {
      const float inv = 1.0f / dn[s][r];
      const size_t row = (size_t)(b * 1024 + qbase + s * 16 + lg * 4 + r);
#pragma unroll
      for (int dt = 0; dt < 4; dt++)
        ctx[row * 1024 + h * 64 + dt * 16 + l15] = (bf16_t)(oacc[s][dt][r] * inv);
    }
  }
}

extern "C" void kernel_launch(void* const* d_in, const int* in_sizes, int n_in,
                              void* d_out, int out_size, void* d_ws, size_t ws_size,
                              hipStream_t stream) {
  (void)in_sizes; (void)n_in; (void)out_size; (void)ws_size;
  const float* x = (const float*)d_in[0];
  const float* w_qkv = (const float*)d_in[1];
  const float* w_out = (const float*)d_in[2];
  float* out = (float*)d_out;
  char* ws = (char*)d_ws;

  bf16_t* x_b   = (bf16_t*)(ws);                        // 16 MB
  bf16_t* qkv_b = (bf16_t*)(ws + (size_t)(16 << 20));   // 48 MB
  bf16_t* wqT   = (bf16_t*)(ws + (size_t)(64 << 20));   // 6 MB
  bf16_t* woT   = (bf16_t*)(ws + (size_t)(70 << 20));   // 2 MB
  bf16_t* ctx_b = (bf16_t*)(ws + (size_t)(72 << 20));   // 16 MB

  const float qsc = 0.045084220027780106f;  // log2(e)/32

  cvt_kernel<<<8388608 / 8 / 256, 256, 0, stream>>>(x, x_b, 8388608 / 8);
  tcvt_kernel<<<dim3(3072 / 32, 1024 / 32), 256, 0, stream>>>(w_qkv, wqT, 1024, 3072);
  tcvt_kernel<<<dim3(1024 / 32, 1024 / 32), 256, 0, stream>>>(w_out, woT, 1024, 1024);

  gemm_qkv_256<<<384, 512, 131072, stream>>>(x_b, wqT, qkv_b, qsc);
  attn_kernel<<<1024, 256, 0, stream>>>(qkv_b, ctx_b);
  gemm_bt_128x256<float><<<256, 512, 147456, stream>>>(
      ctx_b, woT, out, 1024, 64, 0, 1.0f);
}

// Round 13
// 161.075 us; speedup vs baseline: 1.0927x; 1.0033x over previous
//
#include <hip/hip_runtime.h>
#include <hip/hip_bf16.h>

typedef __bf16 bf16_t;
typedef __bf16 bf16x8 __attribute__((ext_vector_type(8)));
typedef __bf16 bf16x4 __attribute__((ext_vector_type(4)));
typedef float f32x4 __attribute__((ext_vector_type(4)));

constexpr int LD = 3072;

#define MFMA_16x16x32(a, b, c) __builtin_amdgcn_mfma_f32_16x16x32_bf16((a), (b), (c), 0, 0, 0)

#define GLOAD_LDS16(g, l)                                               \
  __builtin_amdgcn_global_load_lds(                                     \
      (const __attribute__((address_space(1))) void*)(g),               \
      (__attribute__((address_space(3))) void*)(l), 16, 0, 0)

#define TRREAD(dst, addr, imm) \
  asm volatile("ds_read_b64_tr_b16 %0, %1 offset:" imm : "=v"(dst) : "v"(addr))

#define BAR __builtin_amdgcn_s_barrier()
#define LGKM0 do { asm volatile("s_waitcnt lgkmcnt(0)" ::: "memory"); \
                   __builtin_amdgcn_sched_barrier(0); } while (0)

// ---- fused prep: cvt(x) + tcvt(w_qkv) + tcvt(w_out) in one launch ----
__global__ __launch_bounds__(256) void prep_kernel(
    const float* __restrict__ x, bf16_t* __restrict__ x_b,
    const float* __restrict__ w_qkv, bf16_t* __restrict__ wqT,
    const float* __restrict__ w_out, bf16_t* __restrict__ woT) {
  const int blk = blockIdx.x;
  if (blk < 4096) {  // cvt: 4096*256 threads x 8 floats = 8.39M
    const int i = blk * 256 + threadIdx.x;
    const float4 a = reinterpret_cast<const float4*>(x)[2 * i];
    const float4 c = reinterpret_cast<const float4*>(x)[2 * i + 1];
    bf16x8 o;
    o[0] = (bf16_t)a.x; o[1] = (bf16_t)a.y; o[2] = (bf16_t)a.z; o[3] = (bf16_t)a.w;
    o[4] = (bf16_t)c.x; o[5] = (bf16_t)c.y; o[6] = (bf16_t)c.z; o[7] = (bf16_t)c.w;
    reinterpret_cast<bf16x8*>(x_b)[i] = o;
    return;
  }
  __shared__ float tile[32][33];
  const float* in; bf16_t* outp; int C, bx, by;
  if (blk < 7168) { const int i = blk - 4096; in = w_qkv; outp = wqT; C = 3072; bx = i % 96; by = i / 96; }
  else            { const int i = blk - 7168; in = w_out; outp = woT; C = 1024; bx = i & 31; by = i >> 5; }
  constexpr int R = 1024;
  const int c0 = bx * 32, r0 = by * 32;
  const int tx = threadIdx.x & 31, ty = threadIdx.x >> 5;
#pragma unroll
  for (int i = 0; i < 32; i += 8)
    tile[ty + i][tx] = in[(size_t)(r0 + ty + i) * C + (c0 + tx)];
  __syncthreads();
#pragma unroll
  for (int i = 0; i < 32; i += 8)
    outp[(size_t)(c0 + ty + i) * R + (r0 + tx)] = (bf16_t)tile[tx][ty + i];
}

// ------------- GEMM1 (QKV): 256x256 tile, 8-phase, counted vmcnt (R9) -------
__global__ __launch_bounds__(512, 2) void gemm_qkv_256(
    const bf16_t* __restrict__ A, const bf16_t* __restrict__ Bt,
    bf16_t* __restrict__ C, float q_scale) {
  constexpr int K = 1024;
  extern __shared__ char smem[];
  char* asB = smem;           // 64 KB: A [2][2][128][64]
  char* bsB = smem + 65536;   // 64 KB: B

  const int t = threadIdx.x;
  const int lane = t & 63, wave = t >> 6;
  const int l15 = lane & 15, lg = lane >> 4;
  const int wr = wave >> 2, wc = wave & 3;

  const int bid = blockIdx.x;
  const int wg = (bid & 7) * 48 + (bid >> 3);
  const int brow = (wg & 31) * 256;
  const int bcol = (wg >> 5) * 256;

  const int srow = t >> 3;
  const int schk = (t & 7) ^ (srow & 7);
  const bf16_t* aS = A + (size_t)(brow + srow) * K + schk * 8;
  const bf16_t* bS = Bt + (size_t)(bcol + srow) * K + schk * 8;
  const int ldst = t * 8;

#define STG_A(T, H) do {                                                      \
    const bf16_t* _s = aS + (size_t)((H) * 128) * K + (T) * 64;               \
    bf16_t* _d = (bf16_t*)(asB + ((T) & 1) * 32768 + (H) * 16384) + ldst;     \
    GLOAD_LDS16(_s, _d);                                                      \
    GLOAD_LDS16(_s + (size_t)64 * K, _d + 4096);                              \
  } while (0)
#define STG_B(T, H) do {                                                      \
    const bf16_t* _s = bS + (size_t)((H) * 128) * K + (T) * 64;               \
    bf16_t* _d = (bf16_t*)(bsB + ((T) & 1) * 32768 + (H) * 16384) + ldst;     \
    GLOAD_LDS16(_s, _d);                                                      \
    GLOAD_LDS16(_s + (size_t)64 * K, _d + 4096);                              \
  } while (0)

  const int rx = l15 & 7;
  const unsigned c0 = ((unsigned)(lg ^ rx)) << 4;
  const unsigned c1 = ((unsigned)((4 | lg) ^ rx)) << 4;
  const unsigned a_rd = (unsigned)(wr * 16384 + l15 * 128);
  const unsigned b_rd = (unsigned)((wc >> 1) * 16384 + (wc & 1) * 8192 + l15 * 128);

  f32x4 acc[8][4] = {};
  bf16x8 af[4][2], bfr[2][2];

#define RD_AF(BUF, MH) do { _Pragma("unroll")                                 \
    for (int m = 0; m < 4; ++m) {                                             \
      const char* _p = asB + (BUF) * 32768 + a_rd + ((MH) * 4 + m) * 2048;    \
      af[m][0] = *(const bf16x8*)(_p + c0);                                   \
      af[m][1] = *(const bf16x8*)(_p + c1); } } while (0)
#define RD_BF(BUF, NH) do { _Pragma("unroll")                                 \
    for (int n = 0; n < 2; ++n) {                                             \
      const char* _p = bsB + (BUF) * 32768 + b_rd + ((NH) * 2 + n) * 2048;    \
      bfr[n][0] = *(const bf16x8*)(_p + c0);                                  \
      bfr[n][1] = *(const bf16x8*)(_p + c1); } } while (0)
#define MM16(MH, NH) do {                                                     \
    __builtin_amdgcn_s_setprio(1);                                            \
    _Pragma("unroll")                                                         \
    for (int m = 0; m < 4; ++m) { _Pragma("unroll")                           \
      for (int n = 0; n < 2; ++n) {                                           \
        acc[(MH)*4+m][(NH)*2+n] =                                             \
            MFMA_16x16x32(af[m][0], bfr[n][0], acc[(MH)*4+m][(NH)*2+n]);      \
        acc[(MH)*4+m][(NH)*2+n] =                                             \
            MFMA_16x16x32(af[m][1], bfr[n][1], acc[(MH)*4+m][(NH)*2+n]); } }  \
    __builtin_amdgcn_s_setprio(0); } while (0)

  STG_A(0, 0); STG_A(0, 1); STG_B(0, 0); STG_B(0, 1); STG_A(1, 0);
  asm volatile("s_waitcnt vmcnt(2)" ::: "memory");
  BAR;

  for (int i = 0; i < 8; ++i) {
    const int T1 = 2 * i + 1, T2 = 2 * i + 2, T3 = 2 * i + 3;
    const bool pf = (i < 7);
    STG_A(T1, 1);
    RD_AF(0, 0); RD_BF(0, 0);
    BAR; LGKM0; MM16(0, 0); BAR;
    STG_B(T1, 0);
    RD_BF(0, 1);
    BAR; LGKM0; MM16(0, 1); BAR;
    STG_B(T1, 1);
    RD_AF(0, 1);
    BAR; LGKM0; MM16(1, 1); BAR;
    if (pf) STG_A(T2, 0);
    RD_BF(0, 0);
    BAR; LGKM0; MM16(1, 0);
    if (pf) asm volatile("s_waitcnt vmcnt(2)" ::: "memory");
    else    asm volatile("s_waitcnt vmcnt(0)" ::: "memory");
    BAR;
    if (pf) STG_A(T2, 1);
    RD_AF(1, 0); RD_BF(1, 0);
    BAR; LGKM0; MM16(0, 0); BAR;
    if (pf) STG_B(T2, 0);
    RD_BF(1, 1);
    BAR; LGKM0; MM16(0, 1); BAR;
    if (pf) STG_B(T2, 1);
    RD_AF(1, 1);
    BAR; LGKM0; MM16(1, 1); BAR;
    if (pf) STG_A(T3, 0);
    RD_BF(1, 0);
    BAR; LGKM0; MM16(1, 0);
    asm volatile("s_waitcnt vmcnt(2)" ::: "memory");
    BAR;
  }

  const float sc = (bcol < 1024) ? q_scale : 1.0f;
  const int crow0 = brow + wr * 128 + lg * 4;
  const int ccol0 = bcol + wc * 64 + l15;
#pragma unroll
  for (int m = 0; m < 8; ++m)
#pragma unroll
    for (int n = 0; n < 4; ++n)
#pragma unroll
      for (int r = 0; r < 4; ++r)
        C[(size_t)(crow0 + m * 16 + r) * 3072 + ccol0 + n * 16] =
            (bf16_t)(acc[m][n][r] * sc);
#undef STG_A
#undef STG_B
#undef RD_AF
#undef RD_BF
#undef MM16
}

// ------- GEMM2: 128x256-tile, 4-phase, triple-buffered (R11, grid 256) ------
template <typename OutT>
__global__ __launch_bounds__(512, 1) void gemm_bt_128x256(
    const bf16_t* __restrict__ A, const bf16_t* __restrict__ Bt,
    OutT* __restrict__ C, int N, int nrowblk, int q_cols, float q_scale) {
  constexpr int K = 1024;
  extern __shared__ char smem[];
  char* asB = smem;            // 3 x 16 KB : A [buf][128][64]
  char* bsB = smem + 49152;    // 3 x 32 KB : B [buf][2half][128][64]

  const int t = threadIdx.x;
  const int lane = t & 63, wave = t >> 6;
  const int l15 = lane & 15, lg = lane >> 4;
  const int wr = wave >> 2, wc = wave & 3;

  const int cpx = (int)gridDim.x >> 3;
  const int bid = blockIdx.x;
  const int wg = (bid & 7) * cpx + (bid >> 3);
  const int brow = (wg % nrowblk) * 128;
  const int bcol = (wg / nrowblk) * 256;

  const int srow = t >> 3;
  const int schk = (t & 7) ^ (srow & 7);
  const bf16_t* aS = A + (size_t)(brow + srow) * K + schk * 8;
  const bf16_t* bS = Bt + (size_t)(bcol + srow) * K + schk * 8;
  const int ldst = t * 8;

#define STG_A(T, BUF) do {                                               \
    const bf16_t* _s = aS + (T) * 64;                                    \
    bf16_t* _d = (bf16_t*)(asB + (BUF) * 16384) + ldst;                  \
    GLOAD_LDS16(_s, _d);                                                 \
    GLOAD_LDS16(_s + (size_t)64 * K, _d + 4096);                         \
  } while (0)
#define STG_B(T, H, BUF) do {                                            \
    const bf16_t* _s = bS + (size_t)((H) * 128) * K + (T) * 64;          \
    bf16_t* _d = (bf16_t*)(bsB + (BUF) * 32768 + (H) * 16384) + ldst;    \
    GLOAD_LDS16(_s, _d);                                                 \
    GLOAD_LDS16(_s + (size_t)64 * K, _d + 4096);                         \
  } while (0)

  const int rx = l15 & 7;
  const unsigned c0 = ((unsigned)(lg ^ rx)) << 4;
  const unsigned c1 = ((unsigned)((4 | lg) ^ rx)) << 4;
  const unsigned a_rd = (unsigned)(wr * 8192 + l15 * 128);
  const unsigned b_rd = (unsigned)((wc >> 1) * 16384 + (wc & 1) * 8192 + l15 * 128);

  f32x4 acc[4][4] = {};
  bf16x8 af[2][2], bfr[4][2];

#define RD_AF(BUF, MH) do { _Pragma("unroll")                            \
    for (int m = 0; m < 2; ++m) {                                        \
      const char* _p = asB + (BUF) * 16384 + a_rd + ((MH) * 2 + m) * 2048; \
      af[m][0] = *(const bf16x8*)(_p + c0);                              \
      af[m][1] = *(const bf16x8*)(_p + c1); } } while (0)
#define RD_BF(BUF) do { _Pragma("unroll")                                \
    for (int n = 0; n < 4; ++n) {                                        \
      const char* _p = bsB + (BUF) * 32768 + b_rd + n * 2048;            \
      bfr[n][0] = *(const bf16x8*)(_p + c0);                             \
      bfr[n][1] = *(const bf16x8*)(_p + c1); } } while (0)
#define MM(MH) do {                                                      \
    __builtin_amdgcn_s_setprio(1);                                       \
    _Pragma("unroll")                                                    \
    for (int m = 0; m < 2; ++m) { _Pragma("unroll")                      \
      for (int n = 0; n < 4; ++n) {                                      \
        acc[(MH)*2+m][n] =                                               \
            MFMA_16x16x32(af[m][0], bfr[n][0], acc[(MH)*2+m][n]);        \
        acc[(MH)*2+m][n] =                                               \
            MFMA_16x16x32(af[m][1], bfr[n][1], acc[(MH)*2+m][n]); } }    \
    __builtin_amdgcn_s_setprio(0); } while (0)

  STG_A(0, 0); STG_B(0, 0, 0); STG_B(0, 1, 0);
  STG_A(1, 1); STG_B(1, 0, 1); STG_B(1, 1, 1);
  asm volatile("s_waitcnt vmcnt(6)" ::: "memory");
  BAR;

  int bc = 0;
  for (int T = 0; T < 16; ++T) {
    const bool pf = (T + 2 < 16);
    const int bs = (bc >= 1) ? (bc - 1) : 2;
    if (pf) { STG_A(T + 2, bs); STG_B(T + 2, 0, bs); }
    RD_AF(bc, 0);
    RD_BF(bc);
    BAR; LGKM0; MM(0); BAR;
    if (pf) STG_B(T + 2, 1, bs);
    RD_AF(bc, 1);
    BAR; LGKM0; MM(1);
    if (pf) asm volatile("s_waitcnt vmcnt(6)" ::: "memory");
    else    asm volatile("s_waitcnt vmcnt(0)" ::: "memory");
    BAR;
    bc = (bc == 2) ? 0 : bc + 1;
  }

  const float sc = (bcol < q_cols) ? q_scale : 1.0f;
  const int crow0 = brow + wr * 64 + lg * 4;
  const int ccol0 = bcol + wc * 64 + l15;
#pragma unroll
  for (int m = 0; m < 4; ++m)
#pragma unroll
    for (int n = 0; n < 4; ++n)
#pragma unroll
      for (int r = 0; r < 4; ++r)
        C[(size_t)(crow0 + m * 16 + r) * N + ccol0 + n * 16] =
            (OutT)(acc[m][n][r] * sc);
#undef STG_A
#undef STG_B
#undef RD_AF
#undef RD_BF
#undef MM
}

// ------- fused attention (v11 = v10 + triple-buffer + counted vmcnt) -------
// 3 K/V buffer pairs; stage(t+2) issued at iter t -> 2-iter flight (~800cy).
// Raw s_barrier (no hidden vmcnt(0)); vmcnt(4) at iter end drains st(t+1),
// keeps st(t+2). t=14: vmcnt(0) drains st(15). WAR: stage(t+2) hits
// buf[(t-1)%3], fully read before iter t-1's closing barrier. No VMEM->VGPR
// loads in loop body, so the compiler emits no in-loop vmcnt of its own.
__device__ __forceinline__ unsigned pack_bf16_pair(float a, float b) {
  union { __hip_bfloat162 h; unsigned u; } c;
  c.h = __float22bfloat162_rn(float2{a, b});  // v_cvt_pk_bf16_f32
  return c.u;
}

__global__ __launch_bounds__(256, 3) void attn_kernel(const bf16_t* __restrict__ qkv,
                                                      bf16_t* __restrict__ ctx) {
  __shared__ bf16_t Ks[3][4096];  // swizzled K, triple-buffered (24 KB)
  __shared__ bf16_t Vs[3][4096];  // pi-subtiled V, triple-buffered (24 KB)
  const int tid = threadIdx.x, lane = tid & 63, wave = tid >> 6;
  const int l15 = lane & 15, lg = (lane >> 4) & 3;
  const int flat = blockIdx.x;
  const int xcd = flat & 7, rr = flat >> 3;
  const int qt = rr & 7;
  const int hb = xcd * 16 + (rr >> 3);
  const int h = hb & 15, b = hb >> 4;
  const size_t base = (size_t)b * 1024 * LD;
  const int qbase = qt * 128 + wave * 32;

  bf16x8 qa[2][2];
#pragma unroll
  for (int s = 0; s < 2; s++) {
    const bf16_t* qp = qkv + base + (size_t)(qbase + s * 16 + l15) * LD + h * 64 + lg * 8;
    qa[s][0] = *reinterpret_cast<const bf16x8*>(qp);
    qa[s][1] = *reinterpret_cast<const bf16x8*>(qp + 32);
  }

  const bf16_t* Kb = qkv + base + 1024 + h * 64;
  const bf16_t* Vb = qkv + base + 2048 + h * 64;

  const int krr = lane >> 3;
  const int kcc = (lane & 7) ^ krr;
  const bf16_t* ksrc0 = Kb + (size_t)(wave * 16 + krr) * LD + kcc * 8;
  const bf16_t* ksrc1 = ksrc0 + (size_t)8 * LD;

  const int vd0 = (lane & 1) * 8 + wave * 16;
  const int vkv = ((lane >> 1) & 3) + ((lane >> 3) & 3) * 4 + (lane >> 5) * 16;
  const bf16_t* vsrc0 = Vb + (size_t)vkv * LD + vd0;
  const bf16_t* vsrc1 = vsrc0 + (size_t)32 * LD;

  bf16_t* ksb = &Ks[0][0];
  bf16_t* vsb = &Vs[0][0];
  const char* ksr = (const char*)&Ks[0][0];
  const unsigned vs_byte =
      (unsigned)(size_t)(__attribute__((address_space(3))) void*)(&Vs[0][0]);
  const unsigned tr_lane = vs_byte + lane * 8;

  const int rx7 = l15 & 7;
  const unsigned kb0 = (unsigned)(l15 * 128 + ((lg ^ rx7) << 4));
  const unsigned kb1 = (unsigned)(l15 * 128 + (((4 | lg) ^ rx7) << 4));

  bf16x8 ones;
#pragma unroll
  for (int j = 0; j < 8; j++) ones[j] = (bf16_t)1.0f;

  f32x4 dn[2] = {};
  f32x4 oacc[2][4] = {};

  // stage tile T into buffer BUF (4 gloads/wave)
#define STAGE(BUF, T) do {                                               \
    const size_t _go = (size_t)(T) * 64 * LD;                            \
    bf16_t* _kd = ksb + (BUF) * 4096 + wave * 1024;                      \
    bf16_t* _vd = vsb + (BUF) * 4096 + wave * 1024;                      \
    GLOAD_LDS16(ksrc0 + _go, _kd);                                       \
    GLOAD_LDS16(ksrc1 + _go, _kd + 512);                                 \
    GLOAD_LDS16(vsrc0 + _go, _vd);                                       \
    GLOAD_LDS16(vsrc1 + _go, _vd + 512);                                 \
  } while (0)

  // prologue: stage tiles 0,1 into bufs 0,1; drain st(0), keep st(1)
  STAGE(0, 0);
  STAGE(1, 1);
  asm volatile("s_waitcnt vmcnt(4)" ::: "memory");
  __builtin_amdgcn_sched_barrier(0);
  BAR;

  int bc = 0;  // t % 3
  for (int t = 0; t < 16; t++) {
    const int bsg = (bc == 0) ? 2 : bc - 1;  // (t+2) % 3
    if (t < 14) STAGE(bsg, t + 2);

    f32x4 sacc[2][4] = {};
    const char* kt = ksr + bc * 8192;
    __builtin_amdgcn_s_setprio(1);
#pragma unroll
    for (int tt = 0; tt < 4; tt++) {
      const bf16x8 k0 = *reinterpret_cast<const bf16x8*>(kt + tt * 2048 + kb0);
      const bf16x8 k1 = *reinterpret_cast<const bf16x8*>(kt + tt * 2048 + kb1);
      sacc[0][tt] = MFMA_16x16x32(k0, qa[0][0], sacc[0][tt]);
      sacc[0][tt] = MFMA_16x16x32(k1, qa[0][1], sacc[0][tt]);
      sacc[1][tt] = MFMA_16x16x32(k0, qa[1][0], sacc[1][tt]);
      sacc[1][tt] = MFMA_16x16x32(k1, qa[1][1], sacc[1][tt]);
    }
    __builtin_amdgcn_s_setprio(0);

    const unsigned ta = tr_lane + (unsigned)(bc * 8192);
    bf16x4 tl0, th0, tl2, th2, tl4, th4, tl6, th6;
    TRREAD(tl0, ta, "0");    TRREAD(th0, ta, "512");
    TRREAD(tl2, ta, "2048"); TRREAD(th2, ta, "2560");
    TRREAD(tl4, ta, "4096"); TRREAD(th4, ta, "4608");
    TRREAD(tl6, ta, "6144"); TRREAD(th6, ta, "6656");
    __builtin_amdgcn_sched_barrier(0);

    unsigned pu[16];
#pragma unroll
    for (int tt = 0; tt < 4; tt++) {
      const float a0 = __builtin_exp2f(sacc[0][tt][0]);
      const float a1 = __builtin_exp2f(sacc[0][tt][1]);
      const float a2 = __builtin_exp2f(sacc[0][tt][2]);
      const float a3 = __builtin_exp2f(sacc[0][tt][3]);
      pu[(tt >> 1) * 4 + (tt & 1) * 2 + 0] = pack_bf16_pair(a0, a1);
      pu[(tt >> 1) * 4 + (tt & 1) * 2 + 1] = pack_bf16_pair(a2, a3);
      const float b0 = __builtin_exp2f(sacc[1][tt][0]);
      const float b1 = __builtin_exp2f(sacc[1][tt][1]);
      const float b2 = __builtin_exp2f(sacc[1][tt][2]);
      const float b3 = __builtin_exp2f(sacc[1][tt][3]);
      pu[8 + (tt >> 1) * 4 + (tt & 1) * 2 + 0] = pack_bf16_pair(b0, b1);
      pu[8 + (tt >> 1) * 4 + (tt & 1) * 2 + 1] = pack_bf16_pair(b2, b3);
    }
    bf16x8 pa[2][2];
    pa[0][0] = *reinterpret_cast<bf16x8*>(&pu[0]);
    pa[0][1] = *reinterpret_cast<bf16x8*>(&pu[4]);
    pa[1][0] = *reinterpret_cast<bf16x8*>(&pu[8]);
    pa[1][1] = *reinterpret_cast<bf16x8*>(&pu[12]);

    // denominator rides the matrix pipe
    dn[0] = MFMA_16x16x32(pa[0][0], ones, dn[0]);
    dn[0] = MFMA_16x16x32(pa[0][1], ones, dn[0]);
    dn[1] = MFMA_16x16x32(pa[1][0], ones, dn[1]);
    dn[1] = MFMA_16x16x32(pa[1][1], ones, dn[1]);

    bf16x4 tl1, th1, tl3, th3, tl5, th5, tl7, th7;
    TRREAD(tl1, ta, "1024"); TRREAD(th1, ta, "1536");
    TRREAD(tl3, ta, "3072"); TRREAD(th3, ta, "3584");
    TRREAD(tl5, ta, "5120"); TRREAD(th5, ta, "5632");
    TRREAD(tl7, ta, "7168"); TRREAD(th7, ta, "7680");

    asm volatile("s_waitcnt lgkmcnt(8)" ::: "memory");
    __builtin_amdgcn_sched_barrier(0);
    {
      bf16x8 vb0[4];
      vb0[0] = __builtin_shufflevector(tl0, th0, 0, 1, 2, 3, 4, 5, 6, 7);
      vb0[1] = __builtin_shufflevector(tl2, th2, 0, 1, 2, 3, 4, 5, 6, 7);
      vb0[2] = __builtin_shufflevector(tl4, th4, 0, 1, 2, 3, 4, 5, 6, 7);
      vb0[3] = __builtin_shufflevector(tl6, th6, 0, 1, 2, 3, 4, 5, 6, 7);
      __builtin_amdgcn_s_setprio(1);
#pragma unroll
      for (int s = 0; s < 2; s++)
#pragma unroll
        for (int dt = 0; dt < 4; dt++)
          oacc[s][dt] = MFMA_16x16x32(pa[s][0], vb0[dt], oacc[s][dt]);
      __builtin_amdgcn_s_setprio(0);
    }

    asm volatile("s_waitcnt lgkmcnt(0)" ::: "memory");
    __builtin_amdgcn_sched_barrier(0);
    {
      bf16x8 vb1[4];
      vb1[0] = __builtin_shufflevector(tl1, th1, 0, 1, 2, 3, 4, 5, 6, 7);
      vb1[1] = __builtin_shufflevector(tl3, th3, 0, 1, 2, 3, 4, 5, 6, 7);
      vb1[2] = __builtin_shufflevector(tl5, th5, 0, 1, 2, 3, 4, 5, 6, 7);
      vb1[3] = __builtin_shufflevector(tl7, th7, 0, 1, 2, 3, 4, 5, 6, 7);
      __builtin_amdgcn_s_setprio(1);
#pragma unroll
      for (int s = 0; s < 2; s++)
#pragma unroll
        for (int dt = 0; dt < 4; dt++)
          oacc[s][dt] = MFMA_16x16x32(pa[s][1], vb1[dt], oacc[s][dt]);
      __builtin_amdgcn_s_setprio(0);
    }

    // counted drain: keep st(t+2) in flight across the barrier
    if (t < 14) asm volatile("s_waitcnt vmcnt(4)" ::: "memory");
    else        asm volatile("s_waitcnt vmcnt(0)" ::: "memory");
    __builtin_amdgcn_sched_barrier(0);
    BAR;

    bc = (bc == 2) ? 0 : bc + 1;
  }

  // ---- epilogue: per-lane denominators ----
#pragma unroll
  for (int s = 0; s < 2; s++) {
#pragma unroll
    for (int r = 0; r < 4; r++) {
      const float inv = 1.0f / dn[s][r];
      const size_t row = (size_t)(b * 1024 + qbase + s * 16 + lg * 4 + r);
#pragma unroll
      for (int dt = 0; dt < 4; dt++)
        ctx[row * 1024 + h * 64 + dt * 16 + l15] = (bf16_t)(oacc[s][dt][r] * inv);
    }
  }
#undef STAGE
}

extern "C" void kernel_launch(void* const* d_in, const int* in_sizes, int n_in,
                              void* d_out, int out_size, void* d_ws, size_t ws_size,
                              hipStream_t stream) {
  (void)in_sizes; (void)n_in; (void)out_size; (void)ws_size;
  const float* x = (const float*)d_in[0];
  const float* w_qkv = (const float*)d_in[1];
  const float* w_out = (const float*)d_in[2];
  float* out = (float*)d_out;
  char* ws = (char*)d_ws;

  bf16_t* x_b   = (bf16_t*)(ws);                        // 16 MB
  bf16_t* qkv_b = (bf16_t*)(ws + (size_t)(16 << 20));   // 48 MB
  bf16_t* wqT   = (bf16_t*)(ws + (size_t)(64 << 20));   // 6 MB
  bf16_t* woT   = (bf16_t*)(ws + (size_t)(70 << 20));   // 2 MB
  bf16_t* ctx_b = (bf16_t*)(ws + (size_t)(72 << 20));   // 16 MB

  const float qsc = 0.045084220027780106f;  // log2(e)/32

  prep_kernel<<<8192, 256, 0, stream>>>(x, x_b, w_qkv, wqT, w_out, woT);
  gemm_qkv_256<<<384, 512, 131072, stream>>>(x_b, wqT, qkv_b, qsc);
  attn_kernel<<<1024, 256, 0, stream>>>(qkv_b, ctx_b);
  gemm_bt_128x256<float><<<256, 512, 147456, stream>>>(
      ctx_b, woT, out, 1024, 64, 0, 1.0f);
}